// Round 10
// baseline (12461.154 us; speedup 1.0000x reference)
//
#include <hip/hip_runtime.h>
#include <hip/hip_bf16.h>
#include <cstddef>

typedef _Float16 f16;
typedef f16 f16x8 __attribute__((ext_vector_type(8)));
typedef float f32x4 __attribute__((ext_vector_type(4)));

#define NNODES 10000
#define NEDGES 320000

// ---------------------------------------------------------------------------
// Pack W [Nout][K] (fp32, row-major) into MFMA-B fragment-linear fp16:
// P[((ks*NB + nb)*64 + lane)*8 + i] = W[nb*16 + (lane&15)][ks*32 + 8*(lane>>4) + i]
// ---------------------------------------------------------------------------
__global__ void pack_b(const float* __restrict__ W, f16* __restrict__ P,
                       int Nout, int K) {
    int idx = blockIdx.x * 256 + threadIdx.x;
    int total = Nout * K;
    if (idx >= total) return;
    int i = idx & 7;
    int l = (idx >> 3) & 63;
    int rest = idx >> 9;
    int NB = Nout >> 4;
    int nb = rest % NB;
    int ks = rest / NB;
    int k = ks * 32 + ((l >> 4) << 3) + i;
    int n = nb * 16 + (l & 15);
    P[idx] = (f16)W[(size_t)n * K + k];
}

// ---------------------------------------------------------------------------
// Generic C = A @ W^T + bias. AMODE: 0 = fp32 A (convert), 1 = f16 A.
// OMODE: 0 = f32 out, 1 = f16 out, 2 = f32 out + f16 shadow copy (C2).
// ---------------------------------------------------------------------------
template <int AMODE, int OMODE>
__global__ void gemm_bias(const void* __restrict__ A_, const f16* __restrict__ P,
                          const float* __restrict__ bias, void* __restrict__ C_,
                          f16* __restrict__ C2, int M, int Nout, int K) {
    const int lane = threadIdx.x & 63, wave = threadIdx.x >> 6;
    const int wm = wave >> 1, wn = wave & 1;
    const int rb = blockIdx.x * 64 + wm * 32;
    const int cb = blockIdx.y * 64 + wn * 32;
    const int NB = Nout >> 4;
    const int kl = (lane >> 4) << 3;
    int r0 = rb + (lane & 15);
    int r1 = r0 + 16;
    int rc0 = r0 < M ? r0 : M - 1;
    int rc1 = r1 < M ? r1 : M - 1;
    f32x4 acc[2][2] = {};
    for (int ks = 0; ks < (K >> 5); ++ks) {
        int kb = ks * 32 + kl;
        f16x8 a0, a1;
        if constexpr (AMODE == 1) {
            const f16* A = (const f16*)A_;
            a0 = *(const f16x8*)(A + (size_t)rc0 * K + kb);
            a1 = *(const f16x8*)(A + (size_t)rc1 * K + kb);
        } else {
            const float* A = (const float*)A_;
            const float* p0 = A + (size_t)rc0 * K + kb;
            const float* p1 = A + (size_t)rc1 * K + kb;
#pragma unroll
            for (int i = 0; i < 8; ++i) { a0[i] = (f16)p0[i]; a1[i] = (f16)p1[i]; }
        }
#pragma unroll
        for (int nf = 0; nf < 2; ++nf) {
            int nb = (cb >> 4) + nf;
            f16x8 b = *(const f16x8*)(P + (((size_t)ks * NB + nb) * 64 + lane) * 8);
            acc[0][nf] = __builtin_amdgcn_mfma_f32_16x16x32_f16(a0, b, acc[0][nf], 0, 0, 0);
            acc[1][nf] = __builtin_amdgcn_mfma_f32_16x16x32_f16(a1, b, acc[1][nf], 0, 0, 0);
        }
    }
#pragma unroll
    for (int mf = 0; mf < 2; ++mf)
#pragma unroll
        for (int nf = 0; nf < 2; ++nf)
#pragma unroll
            for (int reg = 0; reg < 4; ++reg) {
                int row = rb + mf * 16 + ((lane >> 4) << 2) + reg;
                int col = cb + nf * 16 + (lane & 15);
                if (row < M) {
                    float v = acc[mf][nf][reg] + bias[col];
                    if constexpr (OMODE == 0) {
                        ((float*)C_)[(size_t)row * Nout + col] = v;
                    } else if constexpr (OMODE == 1) {
                        ((f16*)C_)[(size_t)row * Nout + col] = (f16)v;
                    } else {
                        ((float*)C_)[(size_t)row * Nout + col] = v;
                        C2[(size_t)row * Nout + col] = (f16)v;
                    }
                }
            }
}

// fast activations; tail-safe without clamps (inf handled by rcp -> 0)
__device__ inline float sigmoidf_(float x) {
    return __fdividef(1.f, 1.f + __expf(-x));
}
__device__ inline float tanhf_(float x) {
    float t = __expf(2.f * x);           // inf for large x is fine
    return 1.f - __fdividef(2.f, t + 1.f);
}

// ---------------------------------------------------------------------------
// Fused edge GRU v6, IN-PLACE on uef. Block: 64 edges x 256 cols, 1024 thr =
// 16 waves, wave tile 64 edges x 16 cols (mf=4, nf=1, acc = 64 regs).
// LDS cut to 66 KB (vs 98.8) for 2 blocks/CU = 32 waves/CU: one 32 KB lds_x
// buffer holds the src half of xe for ks 0-7, then is refilled (from 8
// prefetch VGPRs) with the dst half for ks 8-15. lds_h (uef tile) lives to
// phase 2. Epilogue h is re-read from global (L1-hot from staging) instead of
// scattered ds_read_u16 -> fewer LDS bank conflicts.
// acc sets: 0 = ir+hr, 1 = iz+hz, 2 = inn, 3 = hn
// ---------------------------------------------------------------------------
__global__ __launch_bounds__(1024, 8) void edge_gru(
        const f16* __restrict__ unf16, f16* __restrict__ uef,
        const int* __restrict__ src, const int* __restrict__ dst,
        const f16* __restrict__ Pih, const f16* __restrict__ Phh,
        const float* __restrict__ bih, const float* __restrict__ bhh) {
    __shared__ int s_idx[128];
    __shared__ char lds_x[64 * 512];    // xe half-tile (src, then dst), swizzled
    __shared__ char lds_h[64 * 512];    // uef tile, swizzled
    const int t = threadIdx.x;
    const int e0 = blockIdx.x * 64;
    if (t < 64) s_idx[t] = src[e0 + t];
    else if (t < 128) s_idx[t] = dst[e0 + t - 64];
    __syncthreads();
    // stage src rows -> lds_x, uef rows -> lds_h: 64 rows x 32 segs(16B)
    // = 2048 segs / 1024 thr = 2 iters each
    f16x8 dreg[2];
#pragma unroll
    for (int i = 0; i < 2; ++i) {
        int s = t + i * 1024;
        int row = s >> 5, seg = s & 31;
        int sw = (row * 512 + seg * 16) ^ ((row & 7) << 4);
        f16x8 v = *(const f16x8*)(unf16 + (size_t)s_idx[row] * 256 + seg * 8);
        *(f16x8*)(lds_x + sw) = v;
        f16x8 w = *(const f16x8*)(uef + (size_t)(e0 + row) * 256 + seg * 8);
        *(f16x8*)(lds_h + sw) = w;
        // prefetch dst rows; latency drains with staging, written after 1a
        dreg[i] = *(const f16x8*)(unf16 + (size_t)s_idx[64 + row] * 256 + seg * 8);
    }
    __syncthreads();
    const int lane = t & 63;
    const int wn = t >> 6;               // 16 waves, one 16-col group each
    const int klb = (lane >> 4) << 4;    // byte offset of lane's k-slice
    f32x4 acc[4][4] = {};                // [gateset][mf]
    // phase 1a: xe(src half) @ Wih^T, ks = 0..7
#pragma unroll
    for (int ks = 0; ks < 8; ++ks) {
        const int colb = ks * 64 + klb;
        f16x8 a[4];
#pragma unroll
        for (int mf = 0; mf < 4; ++mf) {
            int row = mf * 16 + (lane & 15);
            a[mf] = *(const f16x8*)(lds_x + ((row * 512 + colb) ^ ((row & 7) << 4)));
        }
#pragma unroll
        for (int g = 0; g < 3; ++g) {
            const f16* Pg = Pih + (size_t)g * (512 * 256);
            f16x8 b = *(const f16x8*)(Pg + (((size_t)ks * 16 + wn) * 64 + lane) * 8);
#pragma unroll
            for (int mf = 0; mf < 4; ++mf)
                acc[g][mf] = __builtin_amdgcn_mfma_f32_16x16x32_f16(a[mf], b, acc[g][mf], 0, 0, 0);
        }
    }
    __syncthreads();   // all waves done reading src half
#pragma unroll
    for (int i = 0; i < 2; ++i) {
        int s = t + i * 1024;
        int row = s >> 5, seg = s & 31;
        *(f16x8*)(lds_x + ((row * 512 + seg * 16) ^ ((row & 7) << 4))) = dreg[i];
    }
    __syncthreads();
    // phase 1b: xe(dst half) @ Wih^T, ks = 8..15
#pragma unroll
    for (int ks = 8; ks < 16; ++ks) {
        const int colb = (ks - 8) * 64 + klb;
        f16x8 a[4];
#pragma unroll
        for (int mf = 0; mf < 4; ++mf) {
            int row = mf * 16 + (lane & 15);
            a[mf] = *(const f16x8*)(lds_x + ((row * 512 + colb) ^ ((row & 7) << 4)));
        }
#pragma unroll
        for (int g = 0; g < 3; ++g) {
            const f16* Pg = Pih + (size_t)g * (512 * 256);
            f16x8 b = *(const f16x8*)(Pg + (((size_t)ks * 16 + wn) * 64 + lane) * 8);
#pragma unroll
            for (int mf = 0; mf < 4; ++mf)
                acc[g][mf] = __builtin_amdgcn_mfma_f32_16x16x32_f16(a[mf], b, acc[g][mf], 0, 0, 0);
        }
    }
    // phase 2: h @ Whh^T (K = 256, A = staged uef tile)
#pragma unroll
    for (int ks = 0; ks < 8; ++ks) {
        const int colb = ks * 64 + klb;
        f16x8 a[4];
#pragma unroll
        for (int mf = 0; mf < 4; ++mf) {
            int row = mf * 16 + (lane & 15);
            a[mf] = *(const f16x8*)(lds_h + ((row * 512 + colb) ^ ((row & 7) << 4)));
        }
#pragma unroll
        for (int g = 0; g < 3; ++g) {
            const int tgt = (g == 2) ? 3 : g;
            const f16* Pg = Phh + (size_t)g * (256 * 256);
            f16x8 b = *(const f16x8*)(Pg + (((size_t)ks * 16 + wn) * 64 + lane) * 8);
#pragma unroll
            for (int mf = 0; mf < 4; ++mf)
                acc[tgt][mf] = __builtin_amdgcn_mfma_f32_16x16x32_f16(a[mf], b, acc[tgt][mf], 0, 0, 0);
        }
    }
    // epilogue (h from global uef, L1-hot; per-thread read-then-write of the
    // same element, and no other thread touches it -> race-free in place)
    {
        const int j = wn * 16 + (lane & 15);
        const float b_r = bih[j] + bhh[j];
        const float b_z = bih[256 + j] + bhh[256 + j];
        const float b_i = bih[512 + j];
        const float b_h = bhh[512 + j];
#pragma unroll
        for (int mf = 0; mf < 4; ++mf) {
            const int rloc = mf * 16 + ((lane >> 4) << 2);
#pragma unroll
            for (int reg = 0; reg < 4; ++reg) {
                const int rr = rloc + reg;
                float r = sigmoidf_(acc[0][mf][reg] + b_r);
                float z = sigmoidf_(acc[1][mf][reg] + b_z);
                float nn = tanhf_(acc[2][mf][reg] + b_i + r * (acc[3][mf][reg] + b_h));
                f16* p = uef + (size_t)(e0 + rr) * 256 + j;
                float h = (float)*p;
                *p = (f16)(nn + z * (h - nn));
            }
        }
    }
}

// ---------------------------------------------------------------------------
// Fused node GRU, IN-PLACE on unf (fp32 state); also refreshes f16 shadow.
// Block: 64 nodes x 256 cols, 1024 threads, 16 waves.
// ---------------------------------------------------------------------------
__global__ __launch_bounds__(1024) void node_gru(
        const float* __restrict__ agg, float* __restrict__ unf,
        f16* __restrict__ unf16,
        const f16* __restrict__ Pih, const f16* __restrict__ Phh,
        const float* __restrict__ bih, const float* __restrict__ bhh, int M) {
    const int lane = threadIdx.x & 63, wave = threadIdx.x >> 6;
    const int wm = wave & 1, wn = wave >> 1;
    const int rb = blockIdx.x * 64 + wm * 32;
    const int cb = wn * 32;
    const int nb0 = wn * 2;
    const int kl = (lane >> 4) << 3;
    int r0 = rb + (lane & 15), r1 = r0 + 16;
    int rc0 = r0 < M ? r0 : M - 1;
    int rc1 = r1 < M ? r1 : M - 1;
    f32x4 acc[4][2][2] = {};
#pragma unroll
    for (int ks = 0; ks < 8; ++ks) {
        const float* p0 = agg + (size_t)rc0 * 256 + ks * 32 + kl;
        const float* p1 = agg + (size_t)rc1 * 256 + ks * 32 + kl;
        f16x8 a0, a1;
#pragma unroll
        for (int i = 0; i < 8; ++i) { a0[i] = (f16)p0[i]; a1[i] = (f16)p1[i]; }
#pragma unroll
        for (int g = 0; g < 3; ++g) {
            const f16* Pg = Pih + (size_t)g * (256 * 256);
#pragma unroll
            for (int nf = 0; nf < 2; ++nf) {
                f16x8 b = *(const f16x8*)(Pg + (((size_t)ks * 16 + nb0 + nf) * 64 + lane) * 8);
                acc[g][0][nf] = __builtin_amdgcn_mfma_f32_16x16x32_f16(a0, b, acc[g][0][nf], 0, 0, 0);
                acc[g][1][nf] = __builtin_amdgcn_mfma_f32_16x16x32_f16(a1, b, acc[g][1][nf], 0, 0, 0);
            }
        }
    }
#pragma unroll
    for (int ks = 0; ks < 8; ++ks) {
        const float* p0 = unf + (size_t)rc0 * 256 + ks * 32 + kl;
        const float* p1 = unf + (size_t)rc1 * 256 + ks * 32 + kl;
        f16x8 a0, a1;
#pragma unroll
        for (int i = 0; i < 8; ++i) { a0[i] = (f16)p0[i]; a1[i] = (f16)p1[i]; }
#pragma unroll
        for (int g = 0; g < 3; ++g) {
            const f16* Pg = Phh + (size_t)g * (256 * 256);
            const int tgt = (g == 2) ? 3 : g;
#pragma unroll
            for (int nf = 0; nf < 2; ++nf) {
                f16x8 b = *(const f16x8*)(Pg + (((size_t)ks * 16 + nb0 + nf) * 64 + lane) * 8);
                acc[tgt][0][nf] = __builtin_amdgcn_mfma_f32_16x16x32_f16(a0, b, acc[tgt][0][nf], 0, 0, 0);
                acc[tgt][1][nf] = __builtin_amdgcn_mfma_f32_16x16x32_f16(a1, b, acc[tgt][1][nf], 0, 0, 0);
            }
        }
    }
    __syncthreads();
#pragma unroll
    for (int mf = 0; mf < 2; ++mf) {
        const int row = rb + mf * 16 + ((lane >> 4) << 2);
#pragma unroll
        for (int nf = 0; nf < 2; ++nf) {
            const int j = cb + nf * 16 + (lane & 15);
            const float b_r = bih[j] + bhh[j];
            const float b_z = bih[256 + j] + bhh[256 + j];
            const float b_i = bih[512 + j];
            const float b_h = bhh[512 + j];
#pragma unroll
            for (int reg = 0; reg < 4; ++reg) {
                const int rr = row + reg;
                if (rr < M) {
                    float r = sigmoidf_(acc[0][mf][nf][reg] + b_r);
                    float z = sigmoidf_(acc[1][mf][nf][reg] + b_z);
                    float nn = tanhf_(acc[2][mf][nf][reg] + b_i + r * (acc[3][mf][nf][reg] + b_h));
                    float h = unf[(size_t)rr * 256 + j];     // own region only
                    float v = nn + z * (h - nn);
                    unf[(size_t)rr * 256 + j] = v;
                    unf16[(size_t)rr * 256 + j] = (f16)v;
                }
            }
        }
    }
}

// ---------------------------------------------------------------------------
// CSR build + aggregation (fp32 accumulate, fp32 store)
// ---------------------------------------------------------------------------
__global__ void hist_k(const int* __restrict__ dst, int* __restrict__ cnt, int E) {
    int e = blockIdx.x * 256 + threadIdx.x;
    if (e < E) atomicAdd(&cnt[dst[e]], 1);
}

__global__ void scan_k(const int* __restrict__ cnt, int* __restrict__ rowptr, int n) {
    __shared__ int s[1024];
    __shared__ int carry_s;
    if (threadIdx.x == 0) { carry_s = 0; rowptr[0] = 0; }
    __syncthreads();
    for (int base = 0; base < n; base += 1024) {
        int i = base + (int)threadIdx.x;
        int v = (i < n) ? cnt[i] : 0;
        s[threadIdx.x] = v;
        __syncthreads();
        for (int off = 1; off < 1024; off <<= 1) {
            int tv = (threadIdx.x >= (unsigned)off) ? s[threadIdx.x - off] : 0;
            __syncthreads();
            s[threadIdx.x] += tv;
            __syncthreads();
        }
        if (i < n) rowptr[i + 1] = carry_s + s[threadIdx.x];
        __syncthreads();
        if (threadIdx.x == 0) carry_s += s[1023];
        __syncthreads();
    }
}

__global__ void scatter_k(const int* __restrict__ dst, const int* __restrict__ rowptr,
                          int* __restrict__ cnt2, int* __restrict__ eidx, int E) {
    int e = blockIdx.x * 256 + threadIdx.x;
    if (e < E) {
        int d = dst[e];
        int p = rowptr[d] + atomicAdd(&cnt2[d], 1);
        eidx[p] = e;
    }
}

__global__ void aggregate_k(const f16* __restrict__ uef, const int* __restrict__ eidx,
                            const int* __restrict__ rowptr, float* __restrict__ agg) {
    const int n = blockIdx.x;
    const int c = threadIdx.x;  // 256 threads, one column each
    const int b = rowptr[n], e = rowptr[n + 1];
    float acc = 0.f;
    for (int j = b; j < e; ++j) acc += (float)uef[(size_t)eidx[j] * 256 + c];
    agg[(size_t)n * 256 + c] = acc;
}

// ---------------------------------------------------------------------------
extern "C" void kernel_launch(void* const* d_in, const int* in_sizes, int n_in,
                              void* d_out, int out_size, void* d_ws, size_t ws_size,
                              hipStream_t stream) {
    (void)in_sizes; (void)n_in; (void)out_size; (void)ws_size;
    const float* nf    = (const float*)d_in[0];
    const float* ef    = (const float*)d_in[1];
    const int*   src   = (const int*)d_in[2];
    const int*   dst   = (const int*)d_in[3];
    const float* Wne   = (const float*)d_in[4];
    const float* bne   = (const float*)d_in[5];
    const float* Wee   = (const float*)d_in[6];
    const float* bee   = (const float*)d_in[7];
    const float* Wih_e = (const float*)d_in[8];
    const float* Whh_e = (const float*)d_in[9];
    const float* bih_e = (const float*)d_in[10];
    const float* bhh_e = (const float*)d_in[11];
    const float* Wih_n = (const float*)d_in[12];
    const float* Whh_n = (const float*)d_in[13];
    const float* bih_n = (const float*)d_in[14];
    const float* bhh_n = (const float*)d_in[15];
    const float* Wnd   = (const float*)d_in[16];
    const float* bnd   = (const float*)d_in[17];
    const float* Wed   = (const float*)d_in[18];
    const float* bed   = (const float*)d_in[19];

    char* ws = (char*)d_ws;
    size_t off = 0;
    auto alloc = [&](size_t bytes) -> void* {
        void* p = ws + off;
        off += (bytes + 255) & ~(size_t)255;
        return p;
    };
    // total ~197 MB (well under the ~347 MB proven-working bound)
    f16*   uefA  = (f16*)alloc((size_t)NEDGES * 256 * 2);      // 163.8 MB
    float* unfA  = (float*)alloc((size_t)NNODES * 256 * 4);    // 10.2 MB
    f16*   unf16 = (f16*)alloc((size_t)NNODES * 256 * 2);      // 5.1 MB
    float* agg   = (float*)alloc((size_t)NNODES * 256 * 4);    // 10.2 MB
    f16*   Pih_e = (f16*)alloc((size_t)3 * 512 * 256 * 2);
    f16*   Phh_e = (f16*)alloc((size_t)3 * 256 * 256 * 2);
    f16*   Pih_n = (f16*)alloc((size_t)3 * 256 * 256 * 2);
    f16*   Phh_n = (f16*)alloc((size_t)3 * 256 * 256 * 2);
    f16*   Pne   = (f16*)alloc((size_t)256 * 128 * 2);
    f16*   Pee   = (f16*)alloc((size_t)256 * 64 * 2);
    f16*   Pnd   = (f16*)alloc((size_t)128 * 256 * 2);
    f16*   Ped   = (f16*)alloc((size_t)64 * 256 * 2);
    int* cnt    = (int*)alloc((size_t)NNODES * 4);
    int* cnt2   = (int*)alloc((size_t)NNODES * 4);
    int* rowptr = (int*)alloc((size_t)(NNODES + 1) * 4);
    int* eidx   = (int*)alloc((size_t)NEDGES * 4);

    hipMemsetAsync(cnt, 0, (size_t)NNODES * 4, stream);
    hipMemsetAsync(cnt2, 0, (size_t)NNODES * 4, stream);

    // pack weights
    for (int g = 0; g < 3; ++g) {
        pack_b<<<(256 * 512 + 255) / 256, 256, 0, stream>>>(Wih_e + (size_t)g * 256 * 512,
                                                            Pih_e + (size_t)g * 512 * 256, 256, 512);
        pack_b<<<(256 * 256 + 255) / 256, 256, 0, stream>>>(Whh_e + (size_t)g * 256 * 256,
                                                            Phh_e + (size_t)g * 256 * 256, 256, 256);
        pack_b<<<(256 * 256 + 255) / 256, 256, 0, stream>>>(Wih_n + (size_t)g * 256 * 256,
                                                            Pih_n + (size_t)g * 256 * 256, 256, 256);
        pack_b<<<(256 * 256 + 255) / 256, 256, 0, stream>>>(Whh_n + (size_t)g * 256 * 256,
                                                            Phh_n + (size_t)g * 256 * 256, 256, 256);
    }
    pack_b<<<(256 * 128 + 255) / 256, 256, 0, stream>>>(Wne, Pne, 256, 128);
    pack_b<<<(256 * 64 + 255) / 256, 256, 0, stream>>>(Wee, Pee, 256, 64);
    pack_b<<<(128 * 256 + 255) / 256, 256, 0, stream>>>(Wnd, Pnd, 128, 256);
    pack_b<<<(64 * 256 + 255) / 256, 256, 0, stream>>>(Wed, Ped, 64, 256);

    // CSR by dst
    hist_k<<<(NEDGES + 255) / 256, 256, 0, stream>>>(dst, cnt, NEDGES);
    scan_k<<<1, 1024, 0, stream>>>(cnt, rowptr, NNODES);
    scatter_k<<<(NEDGES + 255) / 256, 256, 0, stream>>>(dst, rowptr, cnt2, eidx, NEDGES);

    // encode (node encoder -> fp32 unf + f16 shadow; edge encoder -> f16 uef)
    gemm_bias<0, 2><<<dim3(157, 4), 256, 0, stream>>>(nf, Pne, bne, unfA, unf16, NNODES, 256, 128);
    gemm_bias<0, 1><<<dim3(5000, 4), 256, 0, stream>>>(ef, Pee, bee, uefA, nullptr, NEDGES, 256, 64);

    // message passing (both GRUs in-place)
    for (int it = 0; it < 3; ++it) {
        edge_gru<<<5000, 1024, 0, stream>>>(unf16, uefA, src, dst, Pih_e, Phh_e, bih_e, bhh_e);
        aggregate_k<<<NNODES, 256, 0, stream>>>(uefA, eidx, rowptr, agg);
        node_gru<<<157, 1024, 0, stream>>>(agg, unfA, unf16, Pih_n, Phh_n, bih_n, bhh_n, NNODES);
    }

    // decode (node from fp32 unf; edge from f16 uef)
    gemm_bias<0, 0><<<dim3(157, 2), 256, 0, stream>>>(unfA, Pnd, bnd, d_out, nullptr, NNODES, 128, 256);
    gemm_bias<1, 0><<<dim3(5000, 1), 256, 0, stream>>>(uefA, Ped, bed,
                                                       (float*)d_out + (size_t)NNODES * 128, nullptr,
                                                       NEDGES, 64, 256);
}

// Round 12
// 2916.235 us; speedup vs baseline: 4.2730x; 4.2730x over previous
//
#include <hip/hip_runtime.h>
#include <hip/hip_bf16.h>
#include <cstddef>

typedef _Float16 f16;
typedef f16 f16x8 __attribute__((ext_vector_type(8)));
typedef float f32x4 __attribute__((ext_vector_type(4)));

#define NNODES 10000
#define NEDGES 320000

// ---------------------------------------------------------------------------
// Pack W [Nout][K] (fp32, row-major) into MFMA-B fragment-linear fp16:
// P[((ks*NB + nb)*64 + lane)*8 + i] = W[nb*16 + (lane&15)][ks*32 + 8*(lane>>4) + i]
// ---------------------------------------------------------------------------
__global__ void pack_b(const float* __restrict__ W, f16* __restrict__ P,
                       int Nout, int K) {
    int idx = blockIdx.x * 256 + threadIdx.x;
    int total = Nout * K;
    if (idx >= total) return;
    int i = idx & 7;
    int l = (idx >> 3) & 63;
    int rest = idx >> 9;
    int NB = Nout >> 4;
    int nb = rest % NB;
    int ks = rest / NB;
    int k = ks * 32 + ((l >> 4) << 3) + i;
    int n = nb * 16 + (l & 15);
    P[idx] = (f16)W[(size_t)n * K + k];
}

// ---------------------------------------------------------------------------
// Generic C = A @ W^T + bias. AMODE: 0 = fp32 A (convert), 1 = f16 A.
// OMODE: 0 = f32 out, 1 = f16 out.
// ---------------------------------------------------------------------------
template <int AMODE, int OMODE>
__global__ void gemm_bias(const void* __restrict__ A_, const f16* __restrict__ P,
                          const float* __restrict__ bias, void* __restrict__ C_,
                          int M, int Nout, int K) {
    const int lane = threadIdx.x & 63, wave = threadIdx.x >> 6;
    const int wm = wave >> 1, wn = wave & 1;
    const int rb = blockIdx.x * 64 + wm * 32;
    const int cb = blockIdx.y * 64 + wn * 32;
    const int NB = Nout >> 4;
    const int kl = (lane >> 4) << 3;
    int r0 = rb + (lane & 15);
    int r1 = r0 + 16;
    int rc0 = r0 < M ? r0 : M - 1;
    int rc1 = r1 < M ? r1 : M - 1;
    f32x4 acc[2][2] = {};
    for (int ks = 0; ks < (K >> 5); ++ks) {
        int kb = ks * 32 + kl;
        f16x8 a0, a1;
        if constexpr (AMODE == 1) {
            const f16* A = (const f16*)A_;
            a0 = *(const f16x8*)(A + (size_t)rc0 * K + kb);
            a1 = *(const f16x8*)(A + (size_t)rc1 * K + kb);
        } else {
            const float* A = (const float*)A_;
            const float* p0 = A + (size_t)rc0 * K + kb;
            const float* p1 = A + (size_t)rc1 * K + kb;
#pragma unroll
            for (int i = 0; i < 8; ++i) { a0[i] = (f16)p0[i]; a1[i] = (f16)p1[i]; }
        }
#pragma unroll
        for (int nf = 0; nf < 2; ++nf) {
            int nb = (cb >> 4) + nf;
            f16x8 b = *(const f16x8*)(P + (((size_t)ks * NB + nb) * 64 + lane) * 8);
            acc[0][nf] = __builtin_amdgcn_mfma_f32_16x16x32_f16(a0, b, acc[0][nf], 0, 0, 0);
            acc[1][nf] = __builtin_amdgcn_mfma_f32_16x16x32_f16(a1, b, acc[1][nf], 0, 0, 0);
        }
    }
#pragma unroll
    for (int mf = 0; mf < 2; ++mf)
#pragma unroll
        for (int nf = 0; nf < 2; ++nf)
#pragma unroll
            for (int reg = 0; reg < 4; ++reg) {
                int row = rb + mf * 16 + ((lane >> 4) << 2) + reg;
                int col = cb + nf * 16 + (lane & 15);
                if (row < M) {
                    float v = acc[mf][nf][reg] + bias[col];
                    if constexpr (OMODE == 0)
                        ((float*)C_)[(size_t)row * Nout + col] = v;
                    else
                        ((f16*)C_)[(size_t)row * Nout + col] = (f16)v;
                }
            }
}

// fast activations; tail-safe without clamps (inf handled by rcp -> 0)
__device__ inline float sigmoidf_(float x) {
    return __fdividef(1.f, 1.f + __expf(-x));
}
__device__ inline float tanhf_(float x) {
    float t = __expf(2.f * x);           // inf for large x is fine
    return 1.f - __fdividef(2.f, t + 1.f);
}

// ---------------------------------------------------------------------------
// Fused edge GRU v8: PING-PONG (reads uef_old, writes uef_new -> no races).
// Block: 64 edges x 128 cols, 512 thr = 8 waves, wave tile 64 edges x 16 cols
// (mf=4, nf=1, acc = 64 regs; ~116 total <= 128 cap). Grid = 10000:
// blockIdx.x = edge_tile*2 + col_half. Sibling blocks duplicate A-staging but
// halve B traffic each (aggregate B unchanged). LDS 66 KB -> 2 blocks/CU =
// 16 waves/CU (the register-law max), and the two resident blocks are
// INDEPENDENT: one block's staging/epilogue overlaps the other's MFMA.
// lds_x (32 KB) holds xe src half for ks 0-7, refilled from 4 prefetch VGPRs
// with the dst half for ks 8-15; lds_h (uef_old tile) feeds phase 2.
// Epilogue h re-read from global uef_old (L1-hot from staging).
// acc sets: 0 = ir+hr, 1 = iz+hz, 2 = inn, 3 = hn
// ---------------------------------------------------------------------------
__global__ __launch_bounds__(512, 4) void edge_gru(
        const f16* __restrict__ unf16,
        const f16* __restrict__ uef_old, f16* __restrict__ uef_new,
        const int* __restrict__ src, const int* __restrict__ dst,
        const f16* __restrict__ Pih, const f16* __restrict__ Phh,
        const float* __restrict__ bih, const float* __restrict__ bhh) {
    __shared__ int s_idx[128];
    __shared__ char lds_x[64 * 512];    // xe half-tile (src, then dst), swizzled
    __shared__ char lds_h[64 * 512];    // uef_old tile, swizzled
    const int t = threadIdx.x;
    const int tile = blockIdx.x >> 1;
    const int ch = blockIdx.x & 1;      // column half: cols [ch*128, ch*128+128)
    const int e0 = tile * 64;
    if (t < 64) s_idx[t] = src[e0 + t];
    else if (t < 128) s_idx[t] = dst[e0 + t - 64];
    __syncthreads();
    // stage src rows -> lds_x, uef_old rows -> lds_h: 64 rows x 32 segs(16B)
    // = 2048 segs / 512 thr = 4 iters each; prefetch dst rows to dreg.
    f16x8 dreg[4];
#pragma unroll
    for (int i = 0; i < 4; ++i) {
        int s = t + i * 512;
        int row = s >> 5, seg = s & 31;
        int sw = (row * 512 + seg * 16) ^ ((row & 7) << 4);
        f16x8 v = *(const f16x8*)(unf16 + (size_t)s_idx[row] * 256 + seg * 8);
        *(f16x8*)(lds_x + sw) = v;
        f16x8 w = *(const f16x8*)(uef_old + (size_t)(e0 + row) * 256 + seg * 8);
        *(f16x8*)(lds_h + sw) = w;
        dreg[i] = *(const f16x8*)(unf16 + (size_t)s_idx[64 + row] * 256 + seg * 8);
    }
    __syncthreads();
    const int lane = t & 63;
    const int jg = ch * 8 + (t >> 6);    // global 16-col group index (0..15)
    const int klb = (lane >> 4) << 4;    // byte offset of lane's k-slice
    f32x4 acc[4][4] = {};                // [gateset][mf]
    // phase 1a: xe(src half) @ Wih^T, ks = 0..7
#pragma unroll
    for (int ks = 0; ks < 8; ++ks) {
        const int colb = ks * 64 + klb;
        f16x8 a[4];
#pragma unroll
        for (int mf = 0; mf < 4; ++mf) {
            int row = mf * 16 + (lane & 15);
            a[mf] = *(const f16x8*)(lds_x + ((row * 512 + colb) ^ ((row & 7) << 4)));
        }
#pragma unroll
        for (int g = 0; g < 3; ++g) {
            const f16* Pg = Pih + (size_t)g * (512 * 256);
            f16x8 b = *(const f16x8*)(Pg + (((size_t)ks * 16 + jg) * 64 + lane) * 8);
#pragma unroll
            for (int mf = 0; mf < 4; ++mf)
                acc[g][mf] = __builtin_amdgcn_mfma_f32_16x16x32_f16(a[mf], b, acc[g][mf], 0, 0, 0);
        }
    }
    __syncthreads();   // all waves done reading src half
#pragma unroll
    for (int i = 0; i < 4; ++i) {
        int s = t + i * 512;
        int row = s >> 5, seg = s & 31;
        *(f16x8*)(lds_x + ((row * 512 + seg * 16) ^ ((row & 7) << 4))) = dreg[i];
    }
    __syncthreads();
    // phase 1b: xe(dst half) @ Wih^T, ks = 8..15
#pragma unroll
    for (int ks = 8; ks < 16; ++ks) {
        const int colb = (ks - 8) * 64 + klb;
        f16x8 a[4];
#pragma unroll
        for (int mf = 0; mf < 4; ++mf) {
            int row = mf * 16 + (lane & 15);
            a[mf] = *(const f16x8*)(lds_x + ((row * 512 + colb) ^ ((row & 7) << 4)));
        }
#pragma unroll
        for (int g = 0; g < 3; ++g) {
            const f16* Pg = Pih + (size_t)g * (512 * 256);
            f16x8 b = *(const f16x8*)(Pg + (((size_t)ks * 16 + jg) * 64 + lane) * 8);
#pragma unroll
            for (int mf = 0; mf < 4; ++mf)
                acc[g][mf] = __builtin_amdgcn_mfma_f32_16x16x32_f16(a[mf], b, acc[g][mf], 0, 0, 0);
        }
    }
    // phase 2: h @ Whh^T (K = 256, A = staged uef_old tile)
#pragma unroll
    for (int ks = 0; ks < 8; ++ks) {
        const int colb = ks * 64 + klb;
        f16x8 a[4];
#pragma unroll
        for (int mf = 0; mf < 4; ++mf) {
            int row = mf * 16 + (lane & 15);
            a[mf] = *(const f16x8*)(lds_h + ((row * 512 + colb) ^ ((row & 7) << 4)));
        }
#pragma unroll
        for (int g = 0; g < 3; ++g) {
            const int tgt = (g == 2) ? 3 : g;
            const f16* Pg = Phh + (size_t)g * (256 * 256);
            f16x8 b = *(const f16x8*)(Pg + (((size_t)ks * 16 + jg) * 64 + lane) * 8);
#pragma unroll
            for (int mf = 0; mf < 4; ++mf)
                acc[tgt][mf] = __builtin_amdgcn_mfma_f32_16x16x32_f16(a[mf], b, acc[tgt][mf], 0, 0, 0);
        }
    }
    // epilogue: h from global uef_old (L1-hot); write uef_new
    {
        const int j = jg * 16 + (lane & 15);
        const float b_r = bih[j] + bhh[j];
        const float b_z = bih[256 + j] + bhh[256 + j];
        const float b_i = bih[512 + j];
        const float b_h = bhh[512 + j];
#pragma unroll
        for (int mf = 0; mf < 4; ++mf) {
            const int rloc = mf * 16 + ((lane >> 4) << 2);
#pragma unroll
            for (int reg = 0; reg < 4; ++reg) {
                const int rr = rloc + reg;
                float r = sigmoidf_(acc[0][mf][reg] + b_r);
                float z = sigmoidf_(acc[1][mf][reg] + b_z);
                float nn = tanhf_(acc[2][mf][reg] + b_i + r * (acc[3][mf][reg] + b_h));
                float h = (float)uef_old[(size_t)(e0 + rr) * 256 + j];
                uef_new[(size_t)(e0 + rr) * 256 + j] = (f16)(nn + z * (h - nn));
            }
        }
    }
}

// ---------------------------------------------------------------------------
// Fused node GRU, IN-PLACE on unf16 (f16 state). Block: 64 nodes x 256 cols,
// 1024 threads, 16 waves; block owns ALL cols of its rows -> in-place safe
// (all reads before the barrier, disjoint writes after).
// ---------------------------------------------------------------------------
__global__ __launch_bounds__(1024) void node_gru(
        const float* __restrict__ agg, f16* __restrict__ unf16,
        const f16* __restrict__ Pih, const f16* __restrict__ Phh,
        const float* __restrict__ bih, const float* __restrict__ bhh, int M) {
    const int lane = threadIdx.x & 63, wave = threadIdx.x >> 6;
    const int wm = wave & 1, wn = wave >> 1;
    const int rb = blockIdx.x * 64 + wm * 32;
    const int cb = wn * 32;
    const int nb0 = wn * 2;
    const int kl = (lane >> 4) << 3;
    int r0 = rb + (lane & 15), r1 = r0 + 16;
    int rc0 = r0 < M ? r0 : M - 1;
    int rc1 = r1 < M ? r1 : M - 1;
    f32x4 acc[4][2][2] = {};
#pragma unroll
    for (int ks = 0; ks < 8; ++ks) {
        const float* p0 = agg + (size_t)rc0 * 256 + ks * 32 + kl;
        const float* p1 = agg + (size_t)rc1 * 256 + ks * 32 + kl;
        f16x8 a0, a1;
#pragma unroll
        for (int i = 0; i < 8; ++i) { a0[i] = (f16)p0[i]; a1[i] = (f16)p1[i]; }
#pragma unroll
        for (int g = 0; g < 3; ++g) {
            const f16* Pg = Pih + (size_t)g * (256 * 256);
#pragma unroll
            for (int nf = 0; nf < 2; ++nf) {
                f16x8 b = *(const f16x8*)(Pg + (((size_t)ks * 16 + nb0 + nf) * 64 + lane) * 8);
                acc[g][0][nf] = __builtin_amdgcn_mfma_f32_16x16x32_f16(a0, b, acc[g][0][nf], 0, 0, 0);
                acc[g][1][nf] = __builtin_amdgcn_mfma_f32_16x16x32_f16(a1, b, acc[g][1][nf], 0, 0, 0);
            }
        }
    }
#pragma unroll
    for (int ks = 0; ks < 8; ++ks) {
        f16x8 a0 = *(const f16x8*)(unf16 + (size_t)rc0 * 256 + ks * 32 + kl);
        f16x8 a1 = *(const f16x8*)(unf16 + (size_t)rc1 * 256 + ks * 32 + kl);
#pragma unroll
        for (int g = 0; g < 3; ++g) {
            const f16* Pg = Phh + (size_t)g * (256 * 256);
            const int tgt = (g == 2) ? 3 : g;
#pragma unroll
            for (int nf = 0; nf < 2; ++nf) {
                f16x8 b = *(const f16x8*)(Pg + (((size_t)ks * 16 + nb0 + nf) * 64 + lane) * 8);
                acc[tgt][0][nf] = __builtin_amdgcn_mfma_f32_16x16x32_f16(a0, b, acc[tgt][0][nf], 0, 0, 0);
                acc[tgt][1][nf] = __builtin_amdgcn_mfma_f32_16x16x32_f16(a1, b, acc[tgt][1][nf], 0, 0, 0);
            }
        }
    }
    __syncthreads();
#pragma unroll
    for (int mf = 0; mf < 2; ++mf) {
        const int row = rb + mf * 16 + ((lane >> 4) << 2);
#pragma unroll
        for (int nf = 0; nf < 2; ++nf) {
            const int j = cb + nf * 16 + (lane & 15);
            const float b_r = bih[j] + bhh[j];
            const float b_z = bih[256 + j] + bhh[256 + j];
            const float b_i = bih[512 + j];
            const float b_h = bhh[512 + j];
#pragma unroll
            for (int reg = 0; reg < 4; ++reg) {
                const int rr = row + reg;
                if (rr < M) {
                    float r = sigmoidf_(acc[0][mf][nf][reg] + b_r);
                    float z = sigmoidf_(acc[1][mf][nf][reg] + b_z);
                    float nn = tanhf_(acc[2][mf][nf][reg] + b_i + r * (acc[3][mf][nf][reg] + b_h));
                    float h = (float)unf16[(size_t)rr * 256 + j];   // own region
                    unf16[(size_t)rr * 256 + j] = (f16)(nn + z * (h - nn));
                }
            }
        }
    }
}

// ---------------------------------------------------------------------------
// CSR build + aggregation (fp32 accumulate, fp32 store)
// ---------------------------------------------------------------------------
__global__ void hist_k(const int* __restrict__ dst, int* __restrict__ cnt, int E) {
    int e = blockIdx.x * 256 + threadIdx.x;
    if (e < E) atomicAdd(&cnt[dst[e]], 1);
}

__global__ void scan_k(const int* __restrict__ cnt, int* __restrict__ rowptr, int n) {
    __shared__ int s[1024];
    __shared__ int carry_s;
    if (threadIdx.x == 0) { carry_s = 0; rowptr[0] = 0; }
    __syncthreads();
    for (int base = 0; base < n; base += 1024) {
        int i = base + (int)threadIdx.x;
        int v = (i < n) ? cnt[i] : 0;
        s[threadIdx.x] = v;
        __syncthreads();
        for (int off = 1; off < 1024; off <<= 1) {
            int tv = (threadIdx.x >= (unsigned)off) ? s[threadIdx.x - off] : 0;
            __syncthreads();
            s[threadIdx.x] += tv;
            __syncthreads();
        }
        if (i < n) rowptr[i + 1] = carry_s + s[threadIdx.x];
        __syncthreads();
        if (threadIdx.x == 0) carry_s += s[1023];
        __syncthreads();
    }
}

__global__ void scatter_k(const int* __restrict__ dst, const int* __restrict__ rowptr,
                          int* __restrict__ cnt2, int* __restrict__ eidx, int E) {
    int e = blockIdx.x * 256 + threadIdx.x;
    if (e < E) {
        int d = dst[e];
        int p = rowptr[d] + atomicAdd(&cnt2[d], 1);
        eidx[p] = e;
    }
}

__global__ void aggregate_k(const f16* __restrict__ uef, const int* __restrict__ eidx,
                            const int* __restrict__ rowptr, float* __restrict__ agg) {
    const int n = blockIdx.x;
    const int c = threadIdx.x;  // 256 threads, one column each
    const int b = rowptr[n], e = rowptr[n + 1];
    float acc = 0.f;
    for (int j = b; j < e; ++j) acc += (float)uef[(size_t)eidx[j] * 256 + c];
    agg[(size_t)n * 256 + c] = acc;
}

// ---------------------------------------------------------------------------
extern "C" void kernel_launch(void* const* d_in, const int* in_sizes, int n_in,
                              void* d_out, int out_size, void* d_ws, size_t ws_size,
                              hipStream_t stream) {
    (void)in_sizes; (void)n_in; (void)out_size; (void)ws_size;
    const float* nf    = (const float*)d_in[0];
    const float* ef    = (const float*)d_in[1];
    const int*   src   = (const int*)d_in[2];
    const int*   dst   = (const int*)d_in[3];
    const float* Wne   = (const float*)d_in[4];
    const float* bne   = (const float*)d_in[5];
    const float* Wee   = (const float*)d_in[6];
    const float* bee   = (const float*)d_in[7];
    const float* Wih_e = (const float*)d_in[8];
    const float* Whh_e = (const float*)d_in[9];
    const float* bih_e = (const float*)d_in[10];
    const float* bhh_e = (const float*)d_in[11];
    const float* Wih_n = (const float*)d_in[12];
    const float* Whh_n = (const float*)d_in[13];
    const float* bih_n = (const float*)d_in[14];
    const float* bhh_n = (const float*)d_in[15];
    const float* Wnd   = (const float*)d_in[16];
    const float* bnd   = (const float*)d_in[17];
    const float* Wed   = (const float*)d_in[18];
    const float* bed   = (const float*)d_in[19];

    char* ws = (char*)d_ws;
    size_t off = 0;
    auto alloc = [&](size_t bytes) -> void* {
        void* p = ws + off;
        off += (bytes + 255) & ~(size_t)255;
        return p;
    };
    // total ~346.6 MB == round-1's proven-working footprint
    f16*   uefA  = (f16*)alloc((size_t)NEDGES * 256 * 2);      // 163.8 MB
    f16*   uefB  = (f16*)alloc((size_t)NEDGES * 256 * 2);      // 163.8 MB
    f16*   unf16 = (f16*)alloc((size_t)NNODES * 256 * 2);      // 5.1 MB
    float* agg   = (float*)alloc((size_t)NNODES * 256 * 4);    // 10.2 MB
    f16*   Pih_e = (f16*)alloc((size_t)3 * 512 * 256 * 2);
    f16*   Phh_e = (f16*)alloc((size_t)3 * 256 * 256 * 2);
    f16*   Pih_n = (f16*)alloc((size_t)3 * 256 * 256 * 2);
    f16*   Phh_n = (f16*)alloc((size_t)3 * 256 * 256 * 2);
    f16*   Pne   = (f16*)alloc((size_t)256 * 128 * 2);
    f16*   Pee   = (f16*)alloc((size_t)256 * 64 * 2);
    f16*   Pnd   = (f16*)alloc((size_t)128 * 256 * 2);
    f16*   Ped   = (f16*)alloc((size_t)64 * 256 * 2);
    int* cnt    = (int*)alloc((size_t)NNODES * 4);
    int* cnt2   = (int*)alloc((size_t)NNODES * 4);
    int* rowptr = (int*)alloc((size_t)(NNODES + 1) * 4);
    int* eidx   = (int*)alloc((size_t)NEDGES * 4);

    hipMemsetAsync(cnt, 0, (size_t)NNODES * 4, stream);
    hipMemsetAsync(cnt2, 0, (size_t)NNODES * 4, stream);

    // pack weights
    for (int g = 0; g < 3; ++g) {
        pack_b<<<(256 * 512 + 255) / 256, 256, 0, stream>>>(Wih_e + (size_t)g * 256 * 512,
                                                            Pih_e + (size_t)g * 512 * 256, 256, 512);
        pack_b<<<(256 * 256 + 255) / 256, 256, 0, stream>>>(Whh_e + (size_t)g * 256 * 256,
                                                            Phh_e + (size_t)g * 256 * 256, 256, 256);
        pack_b<<<(256 * 256 + 255) / 256, 256, 0, stream>>>(Wih_n + (size_t)g * 256 * 256,
                                                            Pih_n + (size_t)g * 256 * 256, 256, 256);
        pack_b<<<(256 * 256 + 255) / 256, 256, 0, stream>>>(Whh_n + (size_t)g * 256 * 256,
                                                            Phh_n + (size_t)g * 256 * 256, 256, 256);
    }
    pack_b<<<(256 * 128 + 255) / 256, 256, 0, stream>>>(Wne, Pne, 256, 128);
    pack_b<<<(256 * 64 + 255) / 256, 256, 0, stream>>>(Wee, Pee, 256, 64);
    pack_b<<<(128 * 256 + 255) / 256, 256, 0, stream>>>(Wnd, Pnd, 128, 256);
    pack_b<<<(64 * 256 + 255) / 256, 256, 0, stream>>>(Wed, Ped, 64, 256);

    // CSR by dst
    hist_k<<<(NEDGES + 255) / 256, 256, 0, stream>>>(dst, cnt, NEDGES);
    scan_k<<<1, 1024, 0, stream>>>(cnt, rowptr, NNODES);
    scatter_k<<<(NEDGES + 255) / 256, 256, 0, stream>>>(dst, rowptr, cnt2, eidx, NEDGES);

    // encode (node encoder -> f16 unf16; edge encoder -> f16 uefA)
    gemm_bias<0, 1><<<dim3(157, 4), 256, 0, stream>>>(nf, Pne, bne, unf16, NNODES, 256, 128);
    gemm_bias<0, 1><<<dim3(5000, 4), 256, 0, stream>>>(ef, Pee, bee, uefA, NEDGES, 256, 64);

    // message passing (edge GRU ping-pong; node GRU in-place on unf16)
    f16 *uef_c = uefA, *uef_n = uefB;
    for (int it = 0; it < 3; ++it) {
        edge_gru<<<10000, 512, 0, stream>>>(unf16, uef_c, uef_n, src, dst,
                                            Pih_e, Phh_e, bih_e, bhh_e);
        aggregate_k<<<NNODES, 256, 0, stream>>>(uef_n, eidx, rowptr, agg);
        node_gru<<<157, 1024, 0, stream>>>(agg, unf16, Pih_n, Phh_n, bih_n, bhh_n, NNODES);
        f16* tmp = uef_c; uef_c = uef_n; uef_n = tmp;
    }

    // decode (node from f16 unf16; edge from final f16 uef)
    gemm_bias<1, 0><<<dim3(157, 2), 256, 0, stream>>>(unf16, Pnd, bnd, d_out, NNODES, 128, 256);
    gemm_bias<1, 0><<<dim3(5000, 1), 256, 0, stream>>>(uef_c, Ped, bed,
                                                       (float*)d_out + (size_t)NNODES * 128,
                                                       NEDGES, 64, 256);
}

// Round 13
// 2108.657 us; speedup vs baseline: 5.9095x; 1.3830x over previous
//
#include <hip/hip_runtime.h>
#include <hip/hip_bf16.h>
#include <cstddef>

typedef _Float16 f16;
typedef f16 f16x8 __attribute__((ext_vector_type(8)));
typedef f16 f16x4 __attribute__((ext_vector_type(4)));
typedef float f32x4 __attribute__((ext_vector_type(4)));

#define NNODES 10000
#define NEDGES 320000

// ---------------------------------------------------------------------------
// Pack W [Nout][ldw] submatrix (cols k0..k0+K) into MFMA-B fragment-linear:
// P[((ks*NB + nb)*64 + lane)*8 + i] = W[(nb*16+(lane&15))*ldw + k0 + ks*32 + 8*(lane>>4) + i]
// ---------------------------------------------------------------------------
__global__ void pack_b(const float* __restrict__ W, f16* __restrict__ P,
                       int Nout, int K, int ldw, int k0) {
    int idx = blockIdx.x * 256 + threadIdx.x;
    int total = Nout * K;
    if (idx >= total) return;
    int i = idx & 7;
    int l = (idx >> 3) & 63;
    int rest = idx >> 9;
    int NB = Nout >> 4;
    int nb = rest % NB;
    int ks = rest / NB;
    int k = ks * 32 + ((l >> 4) << 3) + i;
    int n = nb * 16 + (l & 15);
    P[idx] = (f16)W[(size_t)n * ldw + k0 + k];
}

// ---------------------------------------------------------------------------
// Generic C = A @ W^T + bias. AMODE: 0 = fp32 A (convert), 1 = f16 A.
// OMODE: 0 = f32 out, 1 = f16 out.
// ---------------------------------------------------------------------------
template <int AMODE, int OMODE>
__global__ void gemm_bias(const void* __restrict__ A_, const f16* __restrict__ P,
                          const float* __restrict__ bias, void* __restrict__ C_,
                          int M, int Nout, int K) {
    const int lane = threadIdx.x & 63, wave = threadIdx.x >> 6;
    const int wm = wave >> 1, wn = wave & 1;
    const int rb = blockIdx.x * 64 + wm * 32;
    const int cb = blockIdx.y * 64 + wn * 32;
    const int NB = Nout >> 4;
    const int kl = (lane >> 4) << 3;
    int r0 = rb + (lane & 15);
    int r1 = r0 + 16;
    int rc0 = r0 < M ? r0 : M - 1;
    int rc1 = r1 < M ? r1 : M - 1;
    f32x4 acc[2][2] = {};
    for (int ks = 0; ks < (K >> 5); ++ks) {
        int kb = ks * 32 + kl;
        f16x8 a0, a1;
        if constexpr (AMODE == 1) {
            const f16* A = (const f16*)A_;
            a0 = *(const f16x8*)(A + (size_t)rc0 * K + kb);
            a1 = *(const f16x8*)(A + (size_t)rc1 * K + kb);
        } else {
            const float* A = (const float*)A_;
            const float* p0 = A + (size_t)rc0 * K + kb;
            const float* p1 = A + (size_t)rc1 * K + kb;
#pragma unroll
            for (int i = 0; i < 8; ++i) { a0[i] = (f16)p0[i]; a1[i] = (f16)p1[i]; }
        }
#pragma unroll
        for (int nf = 0; nf < 2; ++nf) {
            int nb = (cb >> 4) + nf;
            f16x8 b = *(const f16x8*)(P + (((size_t)ks * NB + nb) * 64 + lane) * 8);
            acc[0][nf] = __builtin_amdgcn_mfma_f32_16x16x32_f16(a0, b, acc[0][nf], 0, 0, 0);
            acc[1][nf] = __builtin_amdgcn_mfma_f32_16x16x32_f16(a1, b, acc[1][nf], 0, 0, 0);
        }
    }
#pragma unroll
    for (int mf = 0; mf < 2; ++mf)
#pragma unroll
        for (int nf = 0; nf < 2; ++nf)
#pragma unroll
            for (int reg = 0; reg < 4; ++reg) {
                int row = rb + mf * 16 + ((lane >> 4) << 2) + reg;
                int col = cb + nf * 16 + (lane & 15);
                if (row < M) {
                    float v = acc[mf][nf][reg] + bias[col];
                    if constexpr (OMODE == 0)
                        ((float*)C_)[(size_t)row * Nout + col] = v;
                    else
                        ((f16*)C_)[(size_t)row * Nout + col] = (f16)v;
                }
            }
}

// ---------------------------------------------------------------------------
// Per-node message GEMM: G = unf16 @ W^T (+ bias), gate-INTERLEAVED output:
// G[node*1024 + (col&255)*4 + (col>>8)]. Nout = 768, K = 256.
// grid (157, 12), 256 thr.
// ---------------------------------------------------------------------------
template <bool BIAS>
__global__ void gemm_gi(const f16* __restrict__ A, const f16* __restrict__ P,
                        const float* __restrict__ bias, f16* __restrict__ G, int M) {
    const int lane = threadIdx.x & 63, wave = threadIdx.x >> 6;
    const int wm = wave >> 1, wn = wave & 1;
    const int rb = blockIdx.x * 64 + wm * 32;
    const int cb = blockIdx.y * 64 + wn * 32;
    const int NB = 48;                      // 768 / 16
    const int kl = (lane >> 4) << 3;
    int r0 = rb + (lane & 15);
    int r1 = r0 + 16;
    int rc0 = r0 < M ? r0 : M - 1;
    int rc1 = r1 < M ? r1 : M - 1;
    f32x4 acc[2][2] = {};
    for (int ks = 0; ks < 8; ++ks) {
        int kb = ks * 32 + kl;
        f16x8 a0 = *(const f16x8*)(A + (size_t)rc0 * 256 + kb);
        f16x8 a1 = *(const f16x8*)(A + (size_t)rc1 * 256 + kb);
#pragma unroll
        for (int nf = 0; nf < 2; ++nf) {
            int nb = (cb >> 4) + nf;
            f16x8 b = *(const f16x8*)(P + (((size_t)ks * NB + nb) * 64 + lane) * 8);
            acc[0][nf] = __builtin_amdgcn_mfma_f32_16x16x32_f16(a0, b, acc[0][nf], 0, 0, 0);
            acc[1][nf] = __builtin_amdgcn_mfma_f32_16x16x32_f16(a1, b, acc[1][nf], 0, 0, 0);
        }
    }
#pragma unroll
    for (int mf = 0; mf < 2; ++mf)
#pragma unroll
        for (int nf = 0; nf < 2; ++nf)
#pragma unroll
            for (int reg = 0; reg < 4; ++reg) {
                int row = rb + mf * 16 + ((lane >> 4) << 2) + reg;
                int col = cb + nf * 16 + (lane & 15);
                if (row < M) {
                    float v = acc[mf][nf][reg];
                    if constexpr (BIAS) v += bias[col];
                    G[(size_t)row * 1024 + (col & 255) * 4 + (col >> 8)] = (f16)v;
                }
            }
}

// fast activations; tail-safe without clamps (inf handled by rcp -> 0)
__device__ inline float sigmoidf_(float x) {
    return __fdividef(1.f, 1.f + __expf(-x));
}
__device__ inline float tanhf_(float x) {
    float t = __expf(2.f * x);           // inf for large x is fine
    return 1.f - __fdividef(2.f, t + 1.f);
}

// ---------------------------------------------------------------------------
// Fused edge GRU v9: gi comes from precomputed per-node messages Gs/Gd
// (gate-interleaved), so the MFMA part is ONLY gh = uef@Whh^T (126 GFLOP,
// 3x less than before). IN-PLACE on uef: block owns 64 edges x ALL 256 cols;
// the only global uef reads are the staging loads before the single barrier.
// 1024 thr = 16 waves, wave tile 64 edges x 16 cols (mf=4), acc[3][4] = 48.
// LDS: one 64-row uef tile, PADDED stride 528 B (no XOR, bank-conflict-light,
// address = base + compile-time offset). ~34 KB LDS.
// ---------------------------------------------------------------------------
__global__ __launch_bounds__(1024, 4) void edge_gru(
        const f16* __restrict__ Gs, const f16* __restrict__ Gd,
        f16* __restrict__ uef,
        const int* __restrict__ src, const int* __restrict__ dst,
        const f16* __restrict__ Phh, const float* __restrict__ bhh) {
    __shared__ int s_idx[128];
    __shared__ char lds_h[64 * 528];     // uef tile, padded stride
    const int t = threadIdx.x;
    const int e0 = blockIdx.x * 64;
    if (t < 64) s_idx[t] = src[e0 + t];
    else if (t < 128) s_idx[t] = dst[e0 + t - 64];
    // stage uef rows: 64 rows x 32 segs(16B) = 2048 segs / 1024 thr = 2 iters
#pragma unroll
    for (int i = 0; i < 2; ++i) {
        int s = t + i * 1024;
        int row = s >> 5, seg = s & 31;
        f16x8 v = *(const f16x8*)(uef + (size_t)(e0 + row) * 256 + seg * 8);
        *(f16x8*)(lds_h + row * 528 + seg * 16) = v;
    }
    __syncthreads();                     // covers s_idx + staging
    const int lane = t & 63;
    const int wv = t >> 6;               // 16 waves, one 16-col group each
    const int klb = (lane >> 4) << 4;
    const int arow = lane & 15;
    f32x4 acc[3][4] = {};                // [gate hr,hz,hn][mf]
    // gh = uef @ Whh^T  (K = 256)
#pragma unroll
    for (int ks = 0; ks < 8; ++ks) {
        f16x8 a[4];
#pragma unroll
        for (int mf = 0; mf < 4; ++mf)
            a[mf] = *(const f16x8*)(lds_h + (mf * 16 + arow) * 528 + ks * 64 + klb);
#pragma unroll
        for (int g = 0; g < 3; ++g) {
            f16x8 b = *(const f16x8*)(Phh + (size_t)g * 65536
                                      + (((size_t)ks * 16 + wv) * 64 + lane) * 8);
#pragma unroll
            for (int mf = 0; mf < 4; ++mf)
                acc[g][mf] = __builtin_amdgcn_mfma_f32_16x16x32_f16(a[mf], b, acc[g][mf], 0, 0, 0);
        }
    }
    // epilogue: gi gathered from Gs/Gd (one 8B load each, all 3 gates)
    {
        const int j = wv * 16 + (lane & 15);
        const float b_hr = bhh[j];
        const float b_hz = bhh[256 + j];
        const float b_hn = bhh[512 + j];
#pragma unroll
        for (int mf = 0; mf < 4; ++mf) {
            const int rloc = mf * 16 + ((lane >> 4) << 2);
#pragma unroll
            for (int reg = 0; reg < 4; ++reg) {
                const int rr = rloc + reg;
                const int sn = s_idx[rr], dn = s_idx[64 + rr];
                f16x4 gs = *(const f16x4*)(Gs + (size_t)sn * 1024 + j * 4);
                f16x4 gd = *(const f16x4*)(Gd + (size_t)dn * 1024 + j * 4);
                float ir = (float)gs[0] + (float)gd[0];
                float iz = (float)gs[1] + (float)gd[1];
                float in = (float)gs[2] + (float)gd[2];
                float r = sigmoidf_(ir + acc[0][mf][reg] + b_hr);
                float z = sigmoidf_(iz + acc[1][mf][reg] + b_hz);
                float nn = tanhf_(in + r * (acc[2][mf][reg] + b_hn));
                float h = (float)*(const f16*)(lds_h + rr * 528 + j * 2);
                uef[(size_t)(e0 + rr) * 256 + j] = (f16)(nn + z * (h - nn));
            }
        }
    }
}

// ---------------------------------------------------------------------------
// Fused node GRU, IN-PLACE on unf16 (f16 state). Block: 64 nodes x 256 cols,
// 1024 threads, 16 waves; block owns ALL cols of its rows -> in-place safe.
// ---------------------------------------------------------------------------
__global__ __launch_bounds__(1024) void node_gru(
        const float* __restrict__ agg, f16* __restrict__ unf16,
        const f16* __restrict__ Pih, const f16* __restrict__ Phh,
        const float* __restrict__ bih, const float* __restrict__ bhh, int M) {
    const int lane = threadIdx.x & 63, wave = threadIdx.x >> 6;
    const int wm = wave & 1, wn = wave >> 1;
    const int rb = blockIdx.x * 64 + wm * 32;
    const int cb = wn * 32;
    const int nb0 = wn * 2;
    const int kl = (lane >> 4) << 3;
    int r0 = rb + (lane & 15), r1 = r0 + 16;
    int rc0 = r0 < M ? r0 : M - 1;
    int rc1 = r1 < M ? r1 : M - 1;
    f32x4 acc[4][2][2] = {};
#pragma unroll
    for (int ks = 0; ks < 8; ++ks) {
        const float* p0 = agg + (size_t)rc0 * 256 + ks * 32 + kl;
        const float* p1 = agg + (size_t)rc1 * 256 + ks * 32 + kl;
        f16x8 a0, a1;
#pragma unroll
        for (int i = 0; i < 8; ++i) { a0[i] = (f16)p0[i]; a1[i] = (f16)p1[i]; }
#pragma unroll
        for (int g = 0; g < 3; ++g) {
            const f16* Pg = Pih + (size_t)g * (256 * 256);
#pragma unroll
            for (int nf = 0; nf < 2; ++nf) {
                f16x8 b = *(const f16x8*)(Pg + (((size_t)ks * 16 + nb0 + nf) * 64 + lane) * 8);
                acc[g][0][nf] = __builtin_amdgcn_mfma_f32_16x16x32_f16(a0, b, acc[g][0][nf], 0, 0, 0);
                acc[g][1][nf] = __builtin_amdgcn_mfma_f32_16x16x32_f16(a1, b, acc[g][1][nf], 0, 0, 0);
            }
        }
    }
#pragma unroll
    for (int ks = 0; ks < 8; ++ks) {
        f16x8 a0 = *(const f16x8*)(unf16 + (size_t)rc0 * 256 + ks * 32 + kl);
        f16x8 a1 = *(const f16x8*)(unf16 + (size_t)rc1 * 256 + ks * 32 + kl);
#pragma unroll
        for (int g = 0; g < 3; ++g) {
            const f16* Pg = Phh + (size_t)g * (256 * 256);
            const int tgt = (g == 2) ? 3 : g;
#pragma unroll
            for (int nf = 0; nf < 2; ++nf) {
                f16x8 b = *(const f16x8*)(Pg + (((size_t)ks * 16 + nb0 + nf) * 64 + lane) * 8);
                acc[tgt][0][nf] = __builtin_amdgcn_mfma_f32_16x16x32_f16(a0, b, acc[tgt][0][nf], 0, 0, 0);
                acc[tgt][1][nf] = __builtin_amdgcn_mfma_f32_16x16x32_f16(a1, b, acc[tgt][1][nf], 0, 0, 0);
            }
        }
    }
    __syncthreads();
#pragma unroll
    for (int mf = 0; mf < 2; ++mf) {
        const int row = rb + mf * 16 + ((lane >> 4) << 2);
#pragma unroll
        for (int nf = 0; nf < 2; ++nf) {
            const int j = cb + nf * 16 + (lane & 15);
            const float b_r = bih[j] + bhh[j];
            const float b_z = bih[256 + j] + bhh[256 + j];
            const float b_i = bih[512 + j];
            const float b_h = bhh[512 + j];
#pragma unroll
            for (int reg = 0; reg < 4; ++reg) {
                const int rr = row + reg;
                if (rr < M) {
                    float r = sigmoidf_(acc[0][mf][nf][reg] + b_r);
                    float z = sigmoidf_(acc[1][mf][nf][reg] + b_z);
                    float nn = tanhf_(acc[2][mf][nf][reg] + b_i + r * (acc[3][mf][nf][reg] + b_h));
                    float h = (float)unf16[(size_t)rr * 256 + j];   // own region
                    unf16[(size_t)rr * 256 + j] = (f16)(nn + z * (h - nn));
                }
            }
        }
    }
}

// ---------------------------------------------------------------------------
// CSR build + aggregation (fp32 accumulate, fp32 store)
// ---------------------------------------------------------------------------
__global__ void hist_k(const int* __restrict__ dst, int* __restrict__ cnt, int E) {
    int e = blockIdx.x * 256 + threadIdx.x;
    if (e < E) atomicAdd(&cnt[dst[e]], 1);
}

__global__ void scan_k(const int* __restrict__ cnt, int* __restrict__ rowptr, int n) {
    __shared__ int s[1024];
    __shared__ int carry_s;
    if (threadIdx.x == 0) { carry_s = 0; rowptr[0] = 0; }
    __syncthreads();
    for (int base = 0; base < n; base += 1024) {
        int i = base + (int)threadIdx.x;
        int v = (i < n) ? cnt[i] : 0;
        s[threadIdx.x] = v;
        __syncthreads();
        for (int off = 1; off < 1024; off <<= 1) {
            int tv = (threadIdx.x >= (unsigned)off) ? s[threadIdx.x - off] : 0;
            __syncthreads();
            s[threadIdx.x] += tv;
            __syncthreads();
        }
        if (i < n) rowptr[i + 1] = carry_s + s[threadIdx.x];
        __syncthreads();
        if (threadIdx.x == 0) carry_s += s[1023];
        __syncthreads();
    }
}

__global__ void scatter_k(const int* __restrict__ dst, const int* __restrict__ rowptr,
                          int* __restrict__ cnt2, int* __restrict__ eidx, int E) {
    int e = blockIdx.x * 256 + threadIdx.x;
    if (e < E) {
        int d = dst[e];
        int p = rowptr[d] + atomicAdd(&cnt2[d], 1);
        eidx[p] = e;
    }
}

__global__ void aggregate_k(const f16* __restrict__ uef, const int* __restrict__ eidx,
                            const int* __restrict__ rowptr, float* __restrict__ agg) {
    const int n = blockIdx.x;
    const int c = threadIdx.x;  // 256 threads, one column each
    const int b = rowptr[n], e = rowptr[n + 1];
    float acc = 0.f;
    for (int j = b; j < e; ++j) acc += (float)uef[(size_t)eidx[j] * 256 + c];
    agg[(size_t)n * 256 + c] = acc;
}

// ---------------------------------------------------------------------------
extern "C" void kernel_launch(void* const* d_in, const int* in_sizes, int n_in,
                              void* d_out, int out_size, void* d_ws, size_t ws_size,
                              hipStream_t stream) {
    (void)in_sizes; (void)n_in; (void)out_size; (void)ws_size;
    const float* nf    = (const float*)d_in[0];
    const float* ef    = (const float*)d_in[1];
    const int*   src   = (const int*)d_in[2];
    const int*   dst   = (const int*)d_in[3];
    const float* Wne   = (const float*)d_in[4];
    const float* bne   = (const float*)d_in[5];
    const float* Wee   = (const float*)d_in[6];
    const float* bee   = (const float*)d_in[7];
    const float* Wih_e = (const float*)d_in[8];
    const float* Whh_e = (const float*)d_in[9];
    const float* bih_e = (const float*)d_in[10];
    const float* bhh_e = (const float*)d_in[11];
    const float* Wih_n = (const float*)d_in[12];
    const float* Whh_n = (const float*)d_in[13];
    const float* bih_n = (const float*)d_in[14];
    const float* bhh_n = (const float*)d_in[15];
    const float* Wnd   = (const float*)d_in[16];
    const float* bnd   = (const float*)d_in[17];
    const float* Wed   = (const float*)d_in[18];
    const float* bed   = (const float*)d_in[19];

    char* ws = (char*)d_ws;
    size_t off = 0;
    auto alloc = [&](size_t bytes) -> void* {
        void* p = ws + off;
        off += (bytes + 255) & ~(size_t)255;
        return p;
    };
    // total ~244 MB (well under proven ~347 MB bound)
    f16*   uefA  = (f16*)alloc((size_t)NEDGES * 256 * 2);      // 163.8 MB
    f16*   unf16 = (f16*)alloc((size_t)NNODES * 256 * 2);      // 5.1 MB
    float* agg   = (float*)alloc((size_t)NNODES * 256 * 4);    // 10.2 MB
    f16*   Gs    = (f16*)alloc((size_t)NNODES * 1024 * 2);     // 20.5 MB
    f16*   Gd    = (f16*)alloc((size_t)NNODES * 1024 * 2);     // 20.5 MB
    f16*   Ps_e  = (f16*)alloc((size_t)768 * 256 * 2);         // Wih_e[:, :256]
    f16*   Pd_e  = (f16*)alloc((size_t)768 * 256 * 2);         // Wih_e[:, 256:]
    f16*   Phh_e = (f16*)alloc((size_t)3 * 256 * 256 * 2);
    f16*   Pih_n = (f16*)alloc((size_t)3 * 256 * 256 * 2);
    f16*   Phh_n = (f16*)alloc((size_t)3 * 256 * 256 * 2);
    f16*   Pne   = (f16*)alloc((size_t)256 * 128 * 2);
    f16*   Pee   = (f16*)alloc((size_t)256 * 64 * 2);
    f16*   Pnd   = (f16*)alloc((size_t)128 * 256 * 2);
    f16*   Ped   = (f16*)alloc((size_t)64 * 256 * 2);
    int* cnt    = (int*)alloc((size_t)NNODES * 4);
    int* cnt2   = (int*)alloc((size_t)NNODES * 4);
    int* rowptr = (int*)alloc((size_t)(NNODES + 1) * 4);
    int* eidx   = (int*)alloc((size_t)NEDGES * 4);

    hipMemsetAsync(cnt, 0, (size_t)NNODES * 4, stream);
    hipMemsetAsync(cnt2, 0, (size_t)NNODES * 4, stream);

    // pack weights
    pack_b<<<(768 * 256 + 255) / 256, 256, 0, stream>>>(Wih_e, Ps_e, 768, 256, 512, 0);
    pack_b<<<(768 * 256 + 255) / 256, 256, 0, stream>>>(Wih_e, Pd_e, 768, 256, 512, 256);
    for (int g = 0; g < 3; ++g) {
        pack_b<<<(256 * 256 + 255) / 256, 256, 0, stream>>>(Whh_e + (size_t)g * 256 * 256,
                                                            Phh_e + (size_t)g * 256 * 256, 256, 256, 256, 0);
        pack_b<<<(256 * 256 + 255) / 256, 256, 0, stream>>>(Wih_n + (size_t)g * 256 * 256,
                                                            Pih_n + (size_t)g * 256 * 256, 256, 256, 256, 0);
        pack_b<<<(256 * 256 + 255) / 256, 256, 0, stream>>>(Whh_n + (size_t)g * 256 * 256,
                                                            Phh_n + (size_t)g * 256 * 256, 256, 256, 256, 0);
    }
    pack_b<<<(256 * 128 + 255) / 256, 256, 0, stream>>>(Wne, Pne, 256, 128, 128, 0);
    pack_b<<<(256 * 64 + 255) / 256, 256, 0, stream>>>(Wee, Pee, 256, 64, 64, 0);
    pack_b<<<(128 * 256 + 255) / 256, 256, 0, stream>>>(Wnd, Pnd, 128, 256, 256, 0);
    pack_b<<<(64 * 256 + 255) / 256, 256, 0, stream>>>(Wed, Ped, 64, 256, 256, 0);

    // CSR by dst
    hist_k<<<(NEDGES + 255) / 256, 256, 0, stream>>>(dst, cnt, NEDGES);
    scan_k<<<1, 1024, 0, stream>>>(cnt, rowptr, NNODES);
    scatter_k<<<(NEDGES + 255) / 256, 256, 0, stream>>>(dst, rowptr, cnt2, eidx, NEDGES);

    // encode (node encoder -> f16 unf16; edge encoder -> f16 uefA)
    gemm_bias<0, 1><<<dim3(157, 4), 256, 0, stream>>>(nf, Pne, bne, unf16, NNODES, 256, 128);
    gemm_bias<0, 1><<<dim3(5000, 4), 256, 0, stream>>>(ef, Pee, bee, uefA, NEDGES, 256, 64);

    // message passing
    for (int it = 0; it < 3; ++it) {
        // per-node input-gate messages (bih folded into Gs)
        gemm_gi<true ><<<dim3(157, 12), 256, 0, stream>>>(unf16, Ps_e, bih_e, Gs, NNODES);
        gemm_gi<false><<<dim3(157, 12), 256, 0, stream>>>(unf16, Pd_e, bih_e, Gd, NNODES);
        // edge GRU (in-place on uefA)
        edge_gru<<<5000, 1024, 0, stream>>>(Gs, Gd, uefA, src, dst, Phh_e, bhh_e);
        aggregate_k<<<NNODES, 256, 0, stream>>>(uefA, eidx, rowptr, agg);
        node_gru<<<157, 1024, 0, stream>>>(agg, unf16, Pih_n, Phh_n, bih_n, bhh_n, NNODES);
    }

    // decode (node from f16 unf16; edge from f16 uefA)
    gemm_bias<1, 0><<<dim3(157, 2), 256, 0, stream>>>(unf16, Pnd, bnd, d_out, NNODES, 128, 256);
    gemm_bias<1, 0><<<dim3(5000, 1), 256, 0, stream>>>(uefA, Ped, bed,
                                                       (float*)d_out + (size_t)NNODES * 128,
                                                       NEDGES, 64, 256);
}

// Round 14
// 1863.162 us; speedup vs baseline: 6.6882x; 1.1318x over previous
//
#include <hip/hip_runtime.h>
#include <hip/hip_bf16.h>
#include <cstddef>

typedef _Float16 f16;
typedef f16 f16x8 __attribute__((ext_vector_type(8)));
typedef f16 f16x4 __attribute__((ext_vector_type(4)));
typedef f16 f16x16 __attribute__((ext_vector_type(16)));
typedef float f32x4 __attribute__((ext_vector_type(4)));

#define NNODES 10000
#define NEDGES 320000

// ---------------------------------------------------------------------------
// Pack W [Nout][ldw] submatrix (cols k0..k0+K) into MFMA fragment-linear:
// P[((ks*NB + nb)*64 + lane)*8 + i] = W[(nb*16+(lane&15))*ldw + k0 + ks*32 + 8*(lane>>4) + i]
// (Same layout serves as A- or B-fragment: row/col = lane&15, k = 8*(lane>>4)+i.)
// ---------------------------------------------------------------------------
__global__ void pack_b(const float* __restrict__ W, f16* __restrict__ P,
                       int Nout, int K, int ldw, int k0) {
    int idx = blockIdx.x * 256 + threadIdx.x;
    int total = Nout * K;
    if (idx >= total) return;
    int i = idx & 7;
    int l = (idx >> 3) & 63;
    int rest = idx >> 9;
    int NB = Nout >> 4;
    int nb = rest % NB;
    int ks = rest / NB;
    int k = ks * 32 + ((l >> 4) << 3) + i;
    int n = nb * 16 + (l & 15);
    P[idx] = (f16)W[(size_t)n * ldw + k0 + k];
}

// ---------------------------------------------------------------------------
// Generic C = A @ W^T + bias. AMODE: 0 = fp32 A (convert), 1 = f16 A.
// OMODE: 0 = f32 out, 1 = f16 out.
// ---------------------------------------------------------------------------
template <int AMODE, int OMODE>
__global__ void gemm_bias(const void* __restrict__ A_, const f16* __restrict__ P,
                          const float* __restrict__ bias, void* __restrict__ C_,
                          int M, int Nout, int K) {
    const int lane = threadIdx.x & 63, wave = threadIdx.x >> 6;
    const int wm = wave >> 1, wn = wave & 1;
    const int rb = blockIdx.x * 64 + wm * 32;
    const int cb = blockIdx.y * 64 + wn * 32;
    const int NB = Nout >> 4;
    const int kl = (lane >> 4) << 3;
    int r0 = rb + (lane & 15);
    int r1 = r0 + 16;
    int rc0 = r0 < M ? r0 : M - 1;
    int rc1 = r1 < M ? r1 : M - 1;
    f32x4 acc[2][2] = {};
    for (int ks = 0; ks < (K >> 5); ++ks) {
        int kb = ks * 32 + kl;
        f16x8 a0, a1;
        if constexpr (AMODE == 1) {
            const f16* A = (const f16*)A_;
            a0 = *(const f16x8*)(A + (size_t)rc0 * K + kb);
            a1 = *(const f16x8*)(A + (size_t)rc1 * K + kb);
        } else {
            const float* A = (const float*)A_;
            const float* p0 = A + (size_t)rc0 * K + kb;
            const float* p1 = A + (size_t)rc1 * K + kb;
#pragma unroll
            for (int i = 0; i < 8; ++i) { a0[i] = (f16)p0[i]; a1[i] = (f16)p1[i]; }
        }
#pragma unroll
        for (int nf = 0; nf < 2; ++nf) {
            int nb = (cb >> 4) + nf;
            f16x8 b = *(const f16x8*)(P + (((size_t)ks * NB + nb) * 64 + lane) * 8);
            acc[0][nf] = __builtin_amdgcn_mfma_f32_16x16x32_f16(a0, b, acc[0][nf], 0, 0, 0);
            acc[1][nf] = __builtin_amdgcn_mfma_f32_16x16x32_f16(a1, b, acc[1][nf], 0, 0, 0);
        }
    }
#pragma unroll
    for (int mf = 0; mf < 2; ++mf)
#pragma unroll
        for (int nf = 0; nf < 2; ++nf)
#pragma unroll
            for (int reg = 0; reg < 4; ++reg) {
                int row = rb + mf * 16 + ((lane >> 4) << 2) + reg;
                int col = cb + nf * 16 + (lane & 15);
                if (row < M) {
                    float v = acc[mf][nf][reg] + bias[col];
                    if constexpr (OMODE == 0)
                        ((float*)C_)[(size_t)row * Nout + col] = v;
                    else
                        ((f16*)C_)[(size_t)row * Nout + col] = (f16)v;
                }
            }
}

// ---------------------------------------------------------------------------
// Per-node message GEMM: G = unf16 @ W^T (+ bias), gate-INTERLEAVED output:
// G[node*1024 + (col&255)*4 + (col>>8)]. Nout = 768, K = 256.
// ---------------------------------------------------------------------------
template <bool BIAS>
__global__ void gemm_gi(const f16* __restrict__ A, const f16* __restrict__ P,
                        const float* __restrict__ bias, f16* __restrict__ G, int M) {
    const int lane = threadIdx.x & 63, wave = threadIdx.x >> 6;
    const int wm = wave >> 1, wn = wave & 1;
    const int rb = blockIdx.x * 64 + wm * 32;
    const int cb = blockIdx.y * 64 + wn * 32;
    const int NB = 48;
    const int kl = (lane >> 4) << 3;
    int r0 = rb + (lane & 15);
    int r1 = r0 + 16;
    int rc0 = r0 < M ? r0 : M - 1;
    int rc1 = r1 < M ? r1 : M - 1;
    f32x4 acc[2][2] = {};
    for (int ks = 0; ks < 8; ++ks) {
        int kb = ks * 32 + kl;
        f16x8 a0 = *(const f16x8*)(A + (size_t)rc0 * 256 + kb);
        f16x8 a1 = *(const f16x8*)(A + (size_t)rc1 * 256 + kb);
#pragma unroll
        for (int nf = 0; nf < 2; ++nf) {
            int nb = (cb >> 4) + nf;
            f16x8 b = *(const f16x8*)(P + (((size_t)ks * NB + nb) * 64 + lane) * 8);
            acc[0][nf] = __builtin_amdgcn_mfma_f32_16x16x32_f16(a0, b, acc[0][nf], 0, 0, 0);
            acc[1][nf] = __builtin_amdgcn_mfma_f32_16x16x32_f16(a1, b, acc[1][nf], 0, 0, 0);
        }
    }
#pragma unroll
    for (int mf = 0; mf < 2; ++mf)
#pragma unroll
        for (int nf = 0; nf < 2; ++nf)
#pragma unroll
            for (int reg = 0; reg < 4; ++reg) {
                int row = rb + mf * 16 + ((lane >> 4) << 2) + reg;
                int col = cb + nf * 16 + (lane & 15);
                if (row < M) {
                    float v = acc[mf][nf][reg];
                    if constexpr (BIAS) v += bias[col];
                    G[(size_t)row * 1024 + (col & 255) * 4 + (col >> 8)] = (f16)v;
                }
            }
}

// fast activations; tail-safe without clamps (inf handled by rcp -> 0)
__device__ inline float sigmoidf_(float x) {
    return __fdividef(1.f, 1.f + __expf(-x));
}
__device__ inline float tanhf_(float x) {
    float t = __expf(2.f * x);
    return 1.f - __fdividef(2.f, t + 1.f);
}

// ---------------------------------------------------------------------------
// Fused edge GRU v10: TRANSPOSED MFMA (gh^T = Whh @ uef^T). A = Whh fragment
// (row j), B = uef fragment (col edge) -> C: j = (lane>>4)*4+reg (wave's
// 16-j group), edge = lane&15 (per 16-edge group eg). MFMA work = 126 GFLOP.
// Per thread: 4 sn/dn lookups, 8x 32B contiguous G-gathers (gate-interleaved
// layout packs 4j x 4gates in 32 B), results written back to lds_h and copied
// out coalesced (f16x8) -> no partial-line write amplification.
// IN-PLACE on uef: global reads only in staging; writes only in copy-out.
// 1024 thr = 16 waves (one 16-j group each), acc[3][4] = 48 regs, LDS 34 KB.
// ---------------------------------------------------------------------------
__global__ __launch_bounds__(1024, 4) void edge_gru(
        const f16* __restrict__ Gs, const f16* __restrict__ Gd,
        f16* __restrict__ uef,
        const int* __restrict__ src, const int* __restrict__ dst,
        const f16* __restrict__ Phh, const float* __restrict__ bhh) {
    __shared__ int s_idx[128];
    __shared__ char lds_h[64 * 528];
    const int t = threadIdx.x;
    const int e0 = blockIdx.x * 64;
    if (t < 64) s_idx[t] = src[e0 + t];
    else if (t < 128) s_idx[t] = dst[e0 + t - 64];
    // stage uef rows: 64 rows x 32 segs(16B) = 2048 / 1024 = 2 iters
#pragma unroll
    for (int i = 0; i < 2; ++i) {
        int s = t + i * 1024;
        int row = s >> 5, seg = s & 31;
        f16x8 v = *(const f16x8*)(uef + (size_t)(e0 + row) * 256 + seg * 8);
        *(f16x8*)(lds_h + row * 528 + seg * 16) = v;
    }
    __syncthreads();
    const int lane = t & 63;
    const int wv = t >> 6;               // wave's 16-j group (0..15)
    const int klb = (lane >> 4) << 4;    // k-slice byte offset
    const int erow = lane & 15;          // edge within 16-edge group
    f32x4 acc[3][4] = {};                // [gate][edge-group]
    // gh^T = Whh @ uef^T  (K = 256): A = Whh frag (rows j), B = uef frag
#pragma unroll
    for (int ks = 0; ks < 8; ++ks) {
        f16x8 b[4];
#pragma unroll
        for (int eg = 0; eg < 4; ++eg)
            b[eg] = *(const f16x8*)(lds_h + (eg * 16 + erow) * 528 + ks * 64 + klb);
#pragma unroll
        for (int g = 0; g < 3; ++g) {
            f16x8 a = *(const f16x8*)(Phh + (size_t)g * 65536
                                      + (((size_t)ks * 16 + wv) * 64 + lane) * 8);
#pragma unroll
            for (int eg = 0; eg < 4; ++eg)
                acc[g][eg] = __builtin_amdgcn_mfma_f32_16x16x32_f16(a, b[eg], acc[g][eg], 0, 0, 0);
        }
    }
    __syncthreads();   // all MFMA reads of lds_h done before in-place rewrite
    // epilogue: j quad = wv*16 + (lane>>4)*4 + reg, edge = eg*16 + erow
    {
        const int j0 = wv * 16 + ((lane >> 4) << 2);
        const f32x4 bhr = *(const f32x4*)(bhh + j0);
        const f32x4 bhz = *(const f32x4*)(bhh + 256 + j0);
        const f32x4 bhn = *(const f32x4*)(bhh + 512 + j0);
#pragma unroll
        for (int eg = 0; eg < 4; ++eg) {
            const int rr = eg * 16 + erow;
            const int sn = s_idx[rr], dn = s_idx[64 + rr];
            f16x16 gsv = *(const f16x16*)(Gs + (size_t)sn * 1024 + j0 * 4);
            f16x16 gdv = *(const f16x16*)(Gd + (size_t)dn * 1024 + j0 * 4);
            f16x4 hv = *(const f16x4*)(lds_h + rr * 528 + j0 * 2);
            f16x4 outv;
#pragma unroll
            for (int q = 0; q < 4; ++q) {
                float ir = (float)gsv[q * 4 + 0] + (float)gdv[q * 4 + 0];
                float iz = (float)gsv[q * 4 + 1] + (float)gdv[q * 4 + 1];
                float in = (float)gsv[q * 4 + 2] + (float)gdv[q * 4 + 2];
                float r = sigmoidf_(ir + acc[0][eg][q] + bhr[q]);
                float z = sigmoidf_(iz + acc[1][eg][q] + bhz[q]);
                float nn = tanhf_(in + r * (acc[2][eg][q] + bhn[q]));
                float h = (float)hv[q];
                outv[q] = (f16)(nn + z * (h - nn));
            }
            *(f16x4*)(lds_h + rr * 528 + j0 * 2) = outv;   // own (rr, j-quad) only
        }
    }
    __syncthreads();
    // coalesced copy-out
#pragma unroll
    for (int i = 0; i < 2; ++i) {
        int s = t + i * 1024;
        int row = s >> 5, seg = s & 31;
        f16x8 v = *(const f16x8*)(lds_h + row * 528 + seg * 16);
        *(f16x8*)(uef + (size_t)(e0 + row) * 256 + seg * 8) = v;
    }
}

// ---------------------------------------------------------------------------
// Fused node GRU, IN-PLACE on unf16 (f16 state). Block: 64 nodes x 256 cols,
// 1024 threads, 16 waves; block owns ALL cols of its rows -> in-place safe.
// ---------------------------------------------------------------------------
__global__ __launch_bounds__(1024) void node_gru(
        const float* __restrict__ agg, f16* __restrict__ unf16,
        const f16* __restrict__ Pih, const f16* __restrict__ Phh,
        const float* __restrict__ bih, const float* __restrict__ bhh, int M) {
    const int lane = threadIdx.x & 63, wave = threadIdx.x >> 6;
    const int wm = wave & 1, wn = wave >> 1;
    const int rb = blockIdx.x * 64 + wm * 32;
    const int cb = wn * 32;
    const int nb0 = wn * 2;
    const int kl = (lane >> 4) << 3;
    int r0 = rb + (lane & 15), r1 = r0 + 16;
    int rc0 = r0 < M ? r0 : M - 1;
    int rc1 = r1 < M ? r1 : M - 1;
    f32x4 acc[4][2][2] = {};
#pragma unroll
    for (int ks = 0; ks < 8; ++ks) {
        const float* p0 = agg + (size_t)rc0 * 256 + ks * 32 + kl;
        const float* p1 = agg + (size_t)rc1 * 256 + ks * 32 + kl;
        f16x8 a0, a1;
#pragma unroll
        for (int i = 0; i < 8; ++i) { a0[i] = (f16)p0[i]; a1[i] = (f16)p1[i]; }
#pragma unroll
        for (int g = 0; g < 3; ++g) {
            const f16* Pg = Pih + (size_t)g * (256 * 256);
#pragma unroll
            for (int nf = 0; nf < 2; ++nf) {
                f16x8 b = *(const f16x8*)(Pg + (((size_t)ks * 16 + nb0 + nf) * 64 + lane) * 8);
                acc[g][0][nf] = __builtin_amdgcn_mfma_f32_16x16x32_f16(a0, b, acc[g][0][nf], 0, 0, 0);
                acc[g][1][nf] = __builtin_amdgcn_mfma_f32_16x16x32_f16(a1, b, acc[g][1][nf], 0, 0, 0);
            }
        }
    }
#pragma unroll
    for (int ks = 0; ks < 8; ++ks) {
        f16x8 a0 = *(const f16x8*)(unf16 + (size_t)rc0 * 256 + ks * 32 + kl);
        f16x8 a1 = *(const f16x8*)(unf16 + (size_t)rc1 * 256 + ks * 32 + kl);
#pragma unroll
        for (int g = 0; g < 3; ++g) {
            const f16* Pg = Phh + (size_t)g * (256 * 256);
            const int tgt = (g == 2) ? 3 : g;
#pragma unroll
            for (int nf = 0; nf < 2; ++nf) {
                f16x8 b = *(const f16x8*)(Pg + (((size_t)ks * 16 + nb0 + nf) * 64 + lane) * 8);
                acc[tgt][0][nf] = __builtin_amdgcn_mfma_f32_16x16x32_f16(a0, b, acc[tgt][0][nf], 0, 0, 0);
                acc[tgt][1][nf] = __builtin_amdgcn_mfma_f32_16x16x32_f16(a1, b, acc[tgt][1][nf], 0, 0, 0);
            }
        }
    }
    __syncthreads();
#pragma unroll
    for (int mf = 0; mf < 2; ++mf) {
        const int row = rb + mf * 16 + ((lane >> 4) << 2);
#pragma unroll
        for (int nf = 0; nf < 2; ++nf) {
            const int j = cb + nf * 16 + (lane & 15);
            const float b_r = bih[j] + bhh[j];
            const float b_z = bih[256 + j] + bhh[256 + j];
            const float b_i = bih[512 + j];
            const float b_h = bhh[512 + j];
#pragma unroll
            for (int reg = 0; reg < 4; ++reg) {
                const int rr = row + reg;
                if (rr < M) {
                    float r = sigmoidf_(acc[0][mf][nf][reg] + b_r);
                    float z = sigmoidf_(acc[1][mf][nf][reg] + b_z);
                    float nn = tanhf_(acc[2][mf][nf][reg] + b_i + r * (acc[3][mf][nf][reg] + b_h));
                    float h = (float)unf16[(size_t)rr * 256 + j];
                    unf16[(size_t)rr * 256 + j] = (f16)(nn + z * (h - nn));
                }
            }
        }
    }
}

// ---------------------------------------------------------------------------
// CSR build + aggregation (fp32 accumulate, fp32 store)
// ---------------------------------------------------------------------------
__global__ void hist_k(const int* __restrict__ dst, int* __restrict__ cnt, int E) {
    int e = blockIdx.x * 256 + threadIdx.x;
    if (e < E) atomicAdd(&cnt[dst[e]], 1);
}

__global__ void scan_k(const int* __restrict__ cnt, int* __restrict__ rowptr, int n) {
    __shared__ int s[1024];
    __shared__ int carry_s;
    if (threadIdx.x == 0) { carry_s = 0; rowptr[0] = 0; }
    __syncthreads();
    for (int base = 0; base < n; base += 1024) {
        int i = base + (int)threadIdx.x;
        int v = (i < n) ? cnt[i] : 0;
        s[threadIdx.x] = v;
        __syncthreads();
        for (int off = 1; off < 1024; off <<= 1) {
            int tv = (threadIdx.x >= (unsigned)off) ? s[threadIdx.x - off] : 0;
            __syncthreads();
            s[threadIdx.x] += tv;
            __syncthreads();
        }
        if (i < n) rowptr[i + 1] = carry_s + s[threadIdx.x];
        __syncthreads();
        if (threadIdx.x == 0) carry_s += s[1023];
        __syncthreads();
    }
}

__global__ void scatter_k(const int* __restrict__ dst, const int* __restrict__ rowptr,
                          int* __restrict__ cnt2, int* __restrict__ eidx, int E) {
    int e = blockIdx.x * 256 + threadIdx.x;
    if (e < E) {
        int d = dst[e];
        int p = rowptr[d] + atomicAdd(&cnt2[d], 1);
        eidx[p] = e;
    }
}

__global__ void aggregate_k(const f16* __restrict__ uef, const int* __restrict__ eidx,
                            const int* __restrict__ rowptr, float* __restrict__ agg) {
    const int n = blockIdx.x;
    const int c = threadIdx.x;
    const int b = rowptr[n], e = rowptr[n + 1];
    float acc = 0.f;
    for (int j = b; j < e; ++j) acc += (float)uef[(size_t)eidx[j] * 256 + c];
    agg[(size_t)n * 256 + c] = acc;
}

// ---------------------------------------------------------------------------
extern "C" void kernel_launch(void* const* d_in, const int* in_sizes, int n_in,
                              void* d_out, int out_size, void* d_ws, size_t ws_size,
                              hipStream_t stream) {
    (void)in_sizes; (void)n_in; (void)out_size; (void)ws_size;
    const float* nf    = (const float*)d_in[0];
    const float* ef    = (const float*)d_in[1];
    const int*   src   = (const int*)d_in[2];
    const int*   dst   = (const int*)d_in[3];
    const float* Wne   = (const float*)d_in[4];
    const float* bne   = (const float*)d_in[5];
    const float* Wee   = (const float*)d_in[6];
    const float* bee   = (const float*)d_in[7];
    const float* Wih_e = (const float*)d_in[8];
    const float* Whh_e = (const float*)d_in[9];
    const float* bih_e = (const float*)d_in[10];
    const float* bhh_e = (const float*)d_in[11];
    const float* Wih_n = (const float*)d_in[12];
    const float* Whh_n = (const float*)d_in[13];
    const float* bih_n = (const float*)d_in[14];
    const float* bhh_n = (const float*)d_in[15];
    const float* Wnd   = (const float*)d_in[16];
    const float* bnd   = (const float*)d_in[17];
    const float* Wed   = (const float*)d_in[18];
    const float* bed   = (const float*)d_in[19];

    char* ws = (char*)d_ws;
    size_t off = 0;
    auto alloc = [&](size_t bytes) -> void* {
        void* p = ws + off;
        off += (bytes + 255) & ~(size_t)255;
        return p;
    };
    // total ~244 MB (under proven ~347 MB bound)
    f16*   uefA  = (f16*)alloc((size_t)NEDGES * 256 * 2);
    f16*   unf16 = (f16*)alloc((size_t)NNODES * 256 * 2);
    float* agg   = (float*)alloc((size_t)NNODES * 256 * 4);
    f16*   Gs    = (f16*)alloc((size_t)NNODES * 1024 * 2);
    f16*   Gd    = (f16*)alloc((size_t)NNODES * 1024 * 2);
    f16*   Ps_e  = (f16*)alloc((size_t)768 * 256 * 2);
    f16*   Pd_e  = (f16*)alloc((size_t)768 * 256 * 2);
    f16*   Phh_e = (f16*)alloc((size_t)3 * 256 * 256 * 2);
    f16*   Pih_n = (f16*)alloc((size_t)3 * 256 * 256 * 2);
    f16*   Phh_n = (f16*)alloc((size_t)3 * 256 * 256 * 2);
    f16*   Pne   = (f16*)alloc((size_t)256 * 128 * 2);
    f16*   Pee   = (f16*)alloc((size_t)256 * 64 * 2);
    f16*   Pnd   = (f16*)alloc((size_t)128 * 256 * 2);
    f16*   Ped   = (f16*)alloc((size_t)64 * 256 * 2);
    int* cnt    = (int*)alloc((size_t)NNODES * 4);
    int* cnt2   = (int*)alloc((size_t)NNODES * 4);
    int* rowptr = (int*)alloc((size_t)(NNODES + 1) * 4);
    int* eidx   = (int*)alloc((size_t)NEDGES * 4);

    hipMemsetAsync(cnt, 0, (size_t)NNODES * 4, stream);
    hipMemsetAsync(cnt2, 0, (size_t)NNODES * 4, stream);

    // pack weights
    pack_b<<<(768 * 256 + 255) / 256, 256, 0, stream>>>(Wih_e, Ps_e, 768, 256, 512, 0);
    pack_b<<<(768 * 256 + 255) / 256, 256, 0, stream>>>(Wih_e, Pd_e, 768, 256, 512, 256);
    for (int g = 0; g < 3; ++g) {
        pack_b<<<(256 * 256 + 255) / 256, 256, 0, stream>>>(Whh_e + (size_t)g * 256 * 256,
                                                            Phh_e + (size_t)g * 256 * 256, 256, 256, 256, 0);
        pack_b<<<(256 * 256 + 255) / 256, 256, 0, stream>>>(Wih_n + (size_t)g * 256 * 256,
                                                            Pih_n + (size_t)g * 256 * 256, 256, 256, 256, 0);
        pack_b<<<(256 * 256 + 255) / 256, 256, 0, stream>>>(Whh_n + (size_t)g * 256 * 256,
                                                            Phh_n + (size_t)g * 256 * 256, 256, 256, 256, 0);
    }
    pack_b<<<(256 * 128 + 255) / 256, 256, 0, stream>>>(Wne, Pne, 256, 128, 128, 0);
    pack_b<<<(256 * 64 + 255) / 256, 256, 0, stream>>>(Wee, Pee, 256, 64, 64, 0);
    pack_b<<<(128 * 256 + 255) / 256, 256, 0, stream>>>(Wnd, Pnd, 128, 256, 256, 0);
    pack_b<<<(64 * 256 + 255) / 256, 256, 0, stream>>>(Wed, Ped, 64, 256, 256, 0);

    // CSR by dst
    hist_k<<<(NEDGES + 255) / 256, 256, 0, stream>>>(dst, cnt, NEDGES);
    scan_k<<<1, 1024, 0, stream>>>(cnt, rowptr, NNODES);
    scatter_k<<<(NEDGES + 255) / 256, 256, 0, stream>>>(dst, rowptr, cnt2, eidx, NEDGES);

    // encode
    gemm_bias<0, 1><<<dim3(157, 4), 256, 0, stream>>>(nf, Pne, bne, unf16, NNODES, 256, 128);
    gemm_bias<0, 1><<<dim3(5000, 4), 256, 0, stream>>>(ef, Pee, bee, uefA, NEDGES, 256, 64);

    // message passing
    for (int it = 0; it < 3; ++it) {
        gemm_gi<true ><<<dim3(157, 12), 256, 0, stream>>>(unf16, Ps_e, bih_e, Gs, NNODES);
        gemm_gi<false><<<dim3(157, 12), 256, 0, stream>>>(unf16, Pd_e, bih_e, Gd, NNODES);
        edge_gru<<<5000, 1024, 0, stream>>>(Gs, Gd, uefA, src, dst, Phh_e, bhh_e);
        aggregate_k<<<NNODES, 256, 0, stream>>>(uefA, eidx, rowptr, agg);
        node_gru<<<157, 1024, 0, stream>>>(agg, unf16, Pih_n, Phh_n, bih_n, bhh_n, NNODES);
    }

    // decode
    gemm_bias<1, 0><<<dim3(157, 2), 256, 0, stream>>>(unf16, Pnd, bnd, d_out, NNODES, 128, 256);
    gemm_bias<1, 0><<<dim3(5000, 1), 256, 0, stream>>>(uefA, Ped, bed,
                                                       (float*)d_out + (size_t)NNODES * 128,
                                                       NEDGES, 64, 256);
}

// Round 15
// 1752.050 us; speedup vs baseline: 7.1123x; 1.0634x over previous
//
#include <hip/hip_runtime.h>
#include <hip/hip_bf16.h>
#include <cstddef>

typedef _Float16 f16;
typedef f16 f16x8 __attribute__((ext_vector_type(8)));
typedef f16 f16x4 __attribute__((ext_vector_type(4)));
typedef f16 f16x16 __attribute__((ext_vector_type(16)));
typedef float f32x4 __attribute__((ext_vector_type(4)));

#define NNODES 10000
#define NEDGES 320000

// ---------------------------------------------------------------------------
// Pack W [Nout][ldw] submatrix (cols k0..k0+K) into MFMA fragment-linear:
// P[((ks*NB + nb)*64 + lane)*8 + i] = W[(nb*16+(lane&15))*ldw + k0 + ks*32 + 8*(lane>>4) + i]
// ---------------------------------------------------------------------------
__global__ void pack_b(const float* __restrict__ W, f16* __restrict__ P,
                       int Nout, int K, int ldw, int k0) {
    int idx = blockIdx.x * 256 + threadIdx.x;
    int total = Nout * K;
    if (idx >= total) return;
    int i = idx & 7;
    int l = (idx >> 3) & 63;
    int rest = idx >> 9;
    int NB = Nout >> 4;
    int nb = rest % NB;
    int ks = rest / NB;
    int k = ks * 32 + ((l >> 4) << 3) + i;
    int n = nb * 16 + (l & 15);
    P[idx] = (f16)W[(size_t)n * ldw + k0 + k];
}

// ---------------------------------------------------------------------------
// Generic C = A @ W^T + bias. AMODE: 0 = fp32 A (convert), 1 = f16 A.
// OMODE: 0 = f32 out, 1 = f16 out.
// ---------------------------------------------------------------------------
template <int AMODE, int OMODE>
__global__ void gemm_bias(const void* __restrict__ A_, const f16* __restrict__ P,
                          const float* __restrict__ bias, void* __restrict__ C_,
                          int M, int Nout, int K) {
    const int lane = threadIdx.x & 63, wave = threadIdx.x >> 6;
    const int wm = wave >> 1, wn = wave & 1;
    const int rb = blockIdx.x * 64 + wm * 32;
    const int cb = blockIdx.y * 64 + wn * 32;
    const int NB = Nout >> 4;
    const int kl = (lane >> 4) << 3;
    int r0 = rb + (lane & 15);
    int r1 = r0 + 16;
    int rc0 = r0 < M ? r0 : M - 1;
    int rc1 = r1 < M ? r1 : M - 1;
    f32x4 acc[2][2] = {};
    for (int ks = 0; ks < (K >> 5); ++ks) {
        int kb = ks * 32 + kl;
        f16x8 a0, a1;
        if constexpr (AMODE == 1) {
            const f16* A = (const f16*)A_;
            a0 = *(const f16x8*)(A + (size_t)rc0 * K + kb);
            a1 = *(const f16x8*)(A + (size_t)rc1 * K + kb);
        } else {
            const float* A = (const float*)A_;
            const float* p0 = A + (size_t)rc0 * K + kb;
            const float* p1 = A + (size_t)rc1 * K + kb;
#pragma unroll
            for (int i = 0; i < 8; ++i) { a0[i] = (f16)p0[i]; a1[i] = (f16)p1[i]; }
        }
#pragma unroll
        for (int nf = 0; nf < 2; ++nf) {
            int nb = (cb >> 4) + nf;
            f16x8 b = *(const f16x8*)(P + (((size_t)ks * NB + nb) * 64 + lane) * 8);
            acc[0][nf] = __builtin_amdgcn_mfma_f32_16x16x32_f16(a0, b, acc[0][nf], 0, 0, 0);
            acc[1][nf] = __builtin_amdgcn_mfma_f32_16x16x32_f16(a1, b, acc[1][nf], 0, 0, 0);
        }
    }
#pragma unroll
    for (int mf = 0; mf < 2; ++mf)
#pragma unroll
        for (int nf = 0; nf < 2; ++nf)
#pragma unroll
            for (int reg = 0; reg < 4; ++reg) {
                int row = rb + mf * 16 + ((lane >> 4) << 2) + reg;
                int col = cb + nf * 16 + (lane & 15);
                if (row < M) {
                    float v = acc[mf][nf][reg] + bias[col];
                    if constexpr (OMODE == 0)
                        ((float*)C_)[(size_t)row * Nout + col] = v;
                    else
                        ((f16*)C_)[(size_t)row * Nout + col] = (f16)v;
                }
            }
}

// ---------------------------------------------------------------------------
// Fused per-node message GEMMs: Gs = unf16 @ Ws^T + bih, Gd = unf16 @ Wd^T,
// gate-INTERLEAVED output G[node*1024 + (col&255)*4 + (col>>8)].
// grid (157, 24): by<12 -> Gs (with bias), by>=12 -> Gd.
// ---------------------------------------------------------------------------
__global__ void gemm_gi2(const f16* __restrict__ A,
                         const f16* __restrict__ Ps, const f16* __restrict__ Pd,
                         const float* __restrict__ bias,
                         f16* __restrict__ Gs, f16* __restrict__ Gd, int M) {
    const int by = blockIdx.y;
    const bool isD = by >= 12;
    const f16* P = isD ? Pd : Ps;
    f16* G = isD ? Gd : Gs;
    const int byy = isD ? by - 12 : by;
    const int lane = threadIdx.x & 63, wave = threadIdx.x >> 6;
    const int wm = wave >> 1, wn = wave & 1;
    const int rb = blockIdx.x * 64 + wm * 32;
    const int cb = byy * 64 + wn * 32;
    const int NB = 48;
    const int kl = (lane >> 4) << 3;
    int r0 = rb + (lane & 15);
    int r1 = r0 + 16;
    int rc0 = r0 < M ? r0 : M - 1;
    int rc1 = r1 < M ? r1 : M - 1;
    f32x4 acc[2][2] = {};
    for (int ks = 0; ks < 8; ++ks) {
        int kb = ks * 32 + kl;
        f16x8 a0 = *(const f16x8*)(A + (size_t)rc0 * 256 + kb);
        f16x8 a1 = *(const f16x8*)(A + (size_t)rc1 * 256 + kb);
#pragma unroll
        for (int nf = 0; nf < 2; ++nf) {
            int nb = (cb >> 4) + nf;
            f16x8 b = *(const f16x8*)(P + (((size_t)ks * NB + nb) * 64 + lane) * 8);
            acc[0][nf] = __builtin_amdgcn_mfma_f32_16x16x32_f16(a0, b, acc[0][nf], 0, 0, 0);
            acc[1][nf] = __builtin_amdgcn_mfma_f32_16x16x32_f16(a1, b, acc[1][nf], 0, 0, 0);
        }
    }
#pragma unroll
    for (int mf = 0; mf < 2; ++mf)
#pragma unroll
        for (int nf = 0; nf < 2; ++nf)
#pragma unroll
            for (int reg = 0; reg < 4; ++reg) {
                int row = rb + mf * 16 + ((lane >> 4) << 2) + reg;
                int col = cb + nf * 16 + (lane & 15);
                if (row < M) {
                    float v = acc[mf][nf][reg];
                    if (!isD) v += bias[col];
                    G[(size_t)row * 1024 + (col & 255) * 4 + (col >> 8)] = (f16)v;
                }
            }
}

// fast activations; tail-safe without clamps (inf handled by rcp -> 0)
__device__ inline float sigmoidf_(float x) {
    return __fdividef(1.f, 1.f + __expf(-x));
}
__device__ inline float tanhf_(float x) {
    float t = __expf(2.f * x);
    return 1.f - __fdividef(2.f, t + 1.f);
}

// ---------------------------------------------------------------------------
// Fused edge GRU v11 + segment-sum. Processes edges in DST-SORTED order
// (eidx): block owns 64 consecutive sorted positions = 64 distinct edges x
// all 256 cols -> in-place race-free. Transposed MFMA (gh^T = Whh @ uef^T).
// After the epilogue writes uef_new into lds_h, an LDS pass sums same-dst
// RUNS per column (s_dst gives boundaries) and atomicAdds into agg
// (zeroed before launch) -> the separate aggregate kernel disappears and
// uef is never re-read. Copy-out scatters rows to original edge ids.
// 1024 thr = 16 waves, acc[3][4] = 48 regs, LDS ~34 KB.
// ---------------------------------------------------------------------------
__global__ __launch_bounds__(1024, 4) void edge_gru(
        const f16* __restrict__ Gs, const f16* __restrict__ Gd,
        f16* __restrict__ uef,
        const int* __restrict__ src, const int* __restrict__ dst,
        const int* __restrict__ eidx,
        const f16* __restrict__ Phh, const float* __restrict__ bhh,
        float* __restrict__ agg) {
    __shared__ int s_eid[64];
    __shared__ int s_src[64];
    __shared__ int s_dst[64];
    __shared__ char lds_h[64 * 528];
    const int t = threadIdx.x;
    const int p0 = blockIdx.x * 64;
    if (t < 64) {
        int e = eidx[p0 + t];
        s_eid[t] = e;
        s_src[t] = src[e];
        s_dst[t] = dst[e];
    }
    // stage uef rows (gathered by eidx; each staging thread loads its own eid)
#pragma unroll
    for (int i = 0; i < 2; ++i) {
        int s = t + i * 1024;
        int row = s >> 5, seg = s & 31;
        int e = eidx[p0 + row];
        f16x8 v = *(const f16x8*)(uef + (size_t)e * 256 + seg * 8);
        *(f16x8*)(lds_h + row * 528 + seg * 16) = v;
    }
    __syncthreads();
    const int lane = t & 63;
    const int wv = t >> 6;               // wave's 16-j group (0..15)
    const int klb = (lane >> 4) << 4;
    const int erow = lane & 15;
    f32x4 acc[3][4] = {};                // [gate][edge-group]
    // gh^T = Whh @ uef^T  (K = 256)
#pragma unroll
    for (int ks = 0; ks < 8; ++ks) {
        f16x8 b[4];
#pragma unroll
        for (int eg = 0; eg < 4; ++eg)
            b[eg] = *(const f16x8*)(lds_h + (eg * 16 + erow) * 528 + ks * 64 + klb);
#pragma unroll
        for (int g = 0; g < 3; ++g) {
            f16x8 a = *(const f16x8*)(Phh + (size_t)g * 65536
                                      + (((size_t)ks * 16 + wv) * 64 + lane) * 8);
#pragma unroll
            for (int eg = 0; eg < 4; ++eg)
                acc[g][eg] = __builtin_amdgcn_mfma_f32_16x16x32_f16(a, b[eg], acc[g][eg], 0, 0, 0);
        }
    }
    __syncthreads();   // all MFMA reads done before in-place lds_h rewrite
    // epilogue: j quad = wv*16 + (lane>>4)*4 + reg, edge = eg*16 + erow
    {
        const int j0 = wv * 16 + ((lane >> 4) << 2);
        const f32x4 bhr = *(const f32x4*)(bhh + j0);
        const f32x4 bhz = *(const f32x4*)(bhh + 256 + j0);
        const f32x4 bhn = *(const f32x4*)(bhh + 512 + j0);
#pragma unroll
        for (int eg = 0; eg < 4; ++eg) {
            const int rr = eg * 16 + erow;
            const int sn = s_src[rr], dn = s_dst[rr];
            f16x16 gsv = *(const f16x16*)(Gs + (size_t)sn * 1024 + j0 * 4);
            f16x16 gdv = *(const f16x16*)(Gd + (size_t)dn * 1024 + j0 * 4);
            f16x4 hv = *(const f16x4*)(lds_h + rr * 528 + j0 * 2);
            f16x4 outv;
#pragma unroll
            for (int q = 0; q < 4; ++q) {
                float ir = (float)gsv[q * 4 + 0] + (float)gdv[q * 4 + 0];
                float iz = (float)gsv[q * 4 + 1] + (float)gdv[q * 4 + 1];
                float in = (float)gsv[q * 4 + 2] + (float)gdv[q * 4 + 2];
                float r = sigmoidf_(ir + acc[0][eg][q] + bhr[q]);
                float z = sigmoidf_(iz + acc[1][eg][q] + bhz[q]);
                float nn = tanhf_(in + r * (acc[2][eg][q] + bhn[q]));
                float h = (float)hv[q];
                outv[q] = (f16)(nn + z * (h - nn));
            }
            *(f16x4*)(lds_h + rr * 528 + j0 * 2) = outv;
        }
    }
    __syncthreads();
    // coalesced-per-row copy-out (scatter to original edge ids)
#pragma unroll
    for (int i = 0; i < 2; ++i) {
        int s = t + i * 1024;
        int row = s >> 5, seg = s & 31;
        f16x8 v = *(const f16x8*)(lds_h + row * 528 + seg * 16);
        *(f16x8*)(uef + (size_t)s_eid[row] * 256 + seg * 8) = v;
    }
    // fused segment-sum: thread t owns col c, row-quarter q; runs of equal
    // dst are contiguous (sorted) -> flush partial sum at run/quarter ends.
    {
        const int c = t & 255;
        const int q = t >> 8;
        float a = 0.f;
        int d = s_dst[q * 16];
#pragma unroll
        for (int r = q * 16; r < q * 16 + 16; ++r) {
            a += (float)*(const f16*)(lds_h + r * 528 + c * 2);
            int dn = (r < 63) ? s_dst[r + 1] : -1;
            if (r == q * 16 + 15 || dn != d) {
                atomicAdd(&agg[(size_t)d * 256 + c], a);
                a = 0.f;
                d = dn;
            }
        }
    }
}

// ---------------------------------------------------------------------------
// Fused node GRU, IN-PLACE on unf16 (f16 state). Block: 64 nodes x 256 cols.
// ---------------------------------------------------------------------------
__global__ __launch_bounds__(1024) void node_gru(
        const float* __restrict__ agg, f16* __restrict__ unf16,
        const f16* __restrict__ Pih, const f16* __restrict__ Phh,
        const float* __restrict__ bih, const float* __restrict__ bhh, int M) {
    const int lane = threadIdx.x & 63, wave = threadIdx.x >> 6;
    const int wm = wave & 1, wn = wave >> 1;
    const int rb = blockIdx.x * 64 + wm * 32;
    const int cb = wn * 32;
    const int nb0 = wn * 2;
    const int kl = (lane >> 4) << 3;
    int r0 = rb + (lane & 15), r1 = r0 + 16;
    int rc0 = r0 < M ? r0 : M - 1;
    int rc1 = r1 < M ? r1 : M - 1;
    f32x4 acc[4][2][2] = {};
#pragma unroll
    for (int ks = 0; ks < 8; ++ks) {
        const float* p0 = agg + (size_t)rc0 * 256 + ks * 32 + kl;
        const float* p1 = agg + (size_t)rc1 * 256 + ks * 32 + kl;
        f16x8 a0, a1;
#pragma unroll
        for (int i = 0; i < 8; ++i) { a0[i] = (f16)p0[i]; a1[i] = (f16)p1[i]; }
#pragma unroll
        for (int g = 0; g < 3; ++g) {
            const f16* Pg = Pih + (size_t)g * (256 * 256);
#pragma unroll
            for (int nf = 0; nf < 2; ++nf) {
                f16x8 b = *(const f16x8*)(Pg + (((size_t)ks * 16 + nb0 + nf) * 64 + lane) * 8);
                acc[g][0][nf] = __builtin_amdgcn_mfma_f32_16x16x32_f16(a0, b, acc[g][0][nf], 0, 0, 0);
                acc[g][1][nf] = __builtin_amdgcn_mfma_f32_16x16x32_f16(a1, b, acc[g][1][nf], 0, 0, 0);
            }
        }
    }
#pragma unroll
    for (int ks = 0; ks < 8; ++ks) {
        f16x8 a0 = *(const f16x8*)(unf16 + (size_t)rc0 * 256 + ks * 32 + kl);
        f16x8 a1 = *(const f16x8*)(unf16 + (size_t)rc1 * 256 + ks * 32 + kl);
#pragma unroll
        for (int g = 0; g < 3; ++g) {
            const f16* Pg = Phh + (size_t)g * (256 * 256);
            const int tgt = (g == 2) ? 3 : g;
#pragma unroll
            for (int nf = 0; nf < 2; ++nf) {
                f16x8 b = *(const f16x8*)(Pg + (((size_t)ks * 16 + nb0 + nf) * 64 + lane) * 8);
                acc[tgt][0][nf] = __builtin_amdgcn_mfma_f32_16x16x32_f16(a0, b, acc[tgt][0][nf], 0, 0, 0);
                acc[tgt][1][nf] = __builtin_amdgcn_mfma_f32_16x16x32_f16(a1, b, acc[tgt][1][nf], 0, 0, 0);
            }
        }
    }
    __syncthreads();
#pragma unroll
    for (int mf = 0; mf < 2; ++mf) {
        const int row = rb + mf * 16 + ((lane >> 4) << 2);
#pragma unroll
        for (int nf = 0; nf < 2; ++nf) {
            const int j = cb + nf * 16 + (lane & 15);
            const float b_r = bih[j] + bhh[j];
            const float b_z = bih[256 + j] + bhh[256 + j];
            const float b_i = bih[512 + j];
            const float b_h = bhh[512 + j];
#pragma unroll
            for (int reg = 0; reg < 4; ++reg) {
                const int rr = row + reg;
                if (rr < M) {
                    float r = sigmoidf_(acc[0][mf][nf][reg] + b_r);
                    float z = sigmoidf_(acc[1][mf][nf][reg] + b_z);
                    float nn = tanhf_(acc[2][mf][nf][reg] + b_i + r * (acc[3][mf][nf][reg] + b_h));
                    float h = (float)unf16[(size_t)rr * 256 + j];
                    unf16[(size_t)rr * 256 + j] = (f16)(nn + z * (h - nn));
                }
            }
        }
    }
}

// ---------------------------------------------------------------------------
// CSR build (dst-sorted edge order)
// ---------------------------------------------------------------------------
__global__ void hist_k(const int* __restrict__ dst, int* __restrict__ cnt, int E) {
    int e = blockIdx.x * 256 + threadIdx.x;
    if (e < E) atomicAdd(&cnt[dst[e]], 1);
}

__global__ void scan_k(const int* __restrict__ cnt, int* __restrict__ rowptr, int n) {
    __shared__ int s[1024];
    __shared__ int carry_s;
    if (threadIdx.x == 0) { carry_s = 0; rowptr[0] = 0; }
    __syncthreads();
    for (int base = 0; base < n; base += 1024) {
        int i = base + (int)threadIdx.x;
        int v = (i < n) ? cnt[i] : 0;
        s[threadIdx.x] = v;
        __syncthreads();
        for (int off = 1; off < 1024; off <<= 1) {
            int tv = (threadIdx.x >= (unsigned)off) ? s[threadIdx.x - off] : 0;
            __syncthreads();
            s[threadIdx.x] += tv;
            __syncthreads();
        }
        if (i < n) rowptr[i + 1] = carry_s + s[threadIdx.x];
        __syncthreads();
        if (threadIdx.x == 0) carry_s += s[1023];
        __syncthreads();
    }
}

__global__ void scatter_k(const int* __restrict__ dst, const int* __restrict__ rowptr,
                          int* __restrict__ cnt2, int* __restrict__ eidx, int E) {
    int e = blockIdx.x * 256 + threadIdx.x;
    if (e < E) {
        int d = dst[e];
        int p = rowptr[d] + atomicAdd(&cnt2[d], 1);
        eidx[p] = e;
    }
}

// ---------------------------------------------------------------------------
extern "C" void kernel_launch(void* const* d_in, const int* in_sizes, int n_in,
                              void* d_out, int out_size, void* d_ws, size_t ws_size,
                              hipStream_t stream) {
    (void)in_sizes; (void)n_in; (void)out_size; (void)ws_size;
    const float* nf    = (const float*)d_in[0];
    const float* ef    = (const float*)d_in[1];
    const int*   src   = (const int*)d_in[2];
    const int*   dst   = (const int*)d_in[3];
    const float* Wne   = (const float*)d_in[4];
    const float* bne   = (const float*)d_in[5];
    const float* Wee   = (const float*)d_in[6];
    const float* bee   = (const float*)d_in[7];
    const float* Wih_e = (const float*)d_in[8];
    const float* Whh_e = (const float*)d_in[9];
    const float* bih_e = (const float*)d_in[10];
    const float* bhh_e = (const float*)d_in[11];
    const float* Wih_n = (const float*)d_in[12];
    const float* Whh_n = (const float*)d_in[13];
    const float* bih_n = (const float*)d_in[14];
    const float* bhh_n = (const float*)d_in[15];
    const float* Wnd   = (const float*)d_in[16];
    const float* bnd   = (const float*)d_in[17];
    const float* Wed   = (const float*)d_in[18];
    const float* bed   = (const float*)d_in[19];

    char* ws = (char*)d_ws;
    size_t off = 0;
    auto alloc = [&](size_t bytes) -> void* {
        void* p = ws + off;
        off += (bytes + 255) & ~(size_t)255;
        return p;
    };
    // total ~244 MB (under proven ~347 MB bound)
    f16*   uefA  = (f16*)alloc((size_t)NEDGES * 256 * 2);
    f16*   unf16 = (f16*)alloc((size_t)NNODES * 256 * 2);
    float* agg   = (float*)alloc((size_t)NNODES * 256 * 4);
    f16*   Gs    = (f16*)alloc((size_t)NNODES * 1024 * 2);
    f16*   Gd    = (f16*)alloc((size_t)NNODES * 1024 * 2);
    f16*   Ps_e  = (f16*)alloc((size_t)768 * 256 * 2);
    f16*   Pd_e  = (f16*)alloc((size_t)768 * 256 * 2);
    f16*   Phh_e = (f16*)alloc((size_t)3 * 256 * 256 * 2);
    f16*   Pih_n = (f16*)alloc((size_t)3 * 256 * 256 * 2);
    f16*   Phh_n = (f16*)alloc((size_t)3 * 256 * 256 * 2);
    f16*   Pne   = (f16*)alloc((size_t)256 * 128 * 2);
    f16*   Pee   = (f16*)alloc((size_t)256 * 64 * 2);
    f16*   Pnd   = (f16*)alloc((size_t)128 * 256 * 2);
    f16*   Ped   = (f16*)alloc((size_t)64 * 256 * 2);
    int* cnt    = (int*)alloc((size_t)NNODES * 4);
    int* cnt2   = (int*)alloc((size_t)NNODES * 4);
    int* rowptr = (int*)alloc((size_t)(NNODES + 1) * 4);
    int* eidx   = (int*)alloc((size_t)NEDGES * 4);

    hipMemsetAsync(cnt, 0, (size_t)NNODES * 4, stream);
    hipMemsetAsync(cnt2, 0, (size_t)NNODES * 4, stream);

    // pack weights
    pack_b<<<(768 * 256 + 255) / 256, 256, 0, stream>>>(Wih_e, Ps_e, 768, 256, 512, 0);
    pack_b<<<(768 * 256 + 255) / 256, 256, 0, stream>>>(Wih_e, Pd_e, 768, 256, 512, 256);
    for (int g = 0; g < 3; ++g) {
        pack_b<<<(256 * 256 + 255) / 256, 256, 0, stream>>>(Whh_e + (size_t)g * 256 * 256,
                                                            Phh_e + (size_t)g * 256 * 256, 256, 256, 256, 0);
        pack_b<<<(256 * 256 + 255) / 256, 256, 0, stream>>>(Wih_n + (size_t)g * 256 * 256,
                                                            Pih_n + (size_t)g * 256 * 256, 256, 256, 256, 0);
        pack_b<<<(256 * 256 + 255) / 256, 256, 0, stream>>>(Whh_n + (size_t)g * 256 * 256,
                                                            Phh_n + (size_t)g * 256 * 256, 256, 256, 256, 0);
    }
    pack_b<<<(256 * 128 + 255) / 256, 256, 0, stream>>>(Wne, Pne, 256, 128, 128, 0);
    pack_b<<<(256 * 64 + 255) / 256, 256, 0, stream>>>(Wee, Pee, 256, 64, 64, 0);
    pack_b<<<(128 * 256 + 255) / 256, 256, 0, stream>>>(Wnd, Pnd, 128, 256, 256, 0);
    pack_b<<<(64 * 256 + 255) / 256, 256, 0, stream>>>(Wed, Ped, 64, 256, 256, 0);

    // CSR by dst (gives dst-sorted eidx)
    hist_k<<<(NEDGES + 255) / 256, 256, 0, stream>>>(dst, cnt, NEDGES);
    scan_k<<<1, 1024, 0, stream>>>(cnt, rowptr, NNODES);
    scatter_k<<<(NEDGES + 255) / 256, 256, 0, stream>>>(dst, rowptr, cnt2, eidx, NEDGES);

    // encode
    gemm_bias<0, 1><<<dim3(157, 4), 256, 0, stream>>>(nf, Pne, bne, unf16, NNODES, 256, 128);
    gemm_bias<0, 1><<<dim3(5000, 4), 256, 0, stream>>>(ef, Pee, bee, uefA, NEDGES, 256, 64);

    // message passing
    for (int it = 0; it < 3; ++it) {
        gemm_gi2<<<dim3(157, 24), 256, 0, stream>>>(unf16, Ps_e, Pd_e, bih_e, Gs, Gd, NNODES);
        hipMemsetAsync(agg, 0, (size_t)NNODES * 256 * 4, stream);
        edge_gru<<<5000, 1024, 0, stream>>>(Gs, Gd, uefA, src, dst, eidx, Phh_e, bhh_e, agg);
        node_gru<<<157, 1024, 0, stream>>>(agg, unf16, Pih_n, Phh_n, bih_n, bhh_n, NNODES);
    }

    // decode
    gemm_bias<1, 0><<<dim3(157, 2), 256, 0, stream>>>(unf16, Pnd, bnd, d_out, NNODES, 128, 256);
    gemm_bias<1, 0><<<dim3(5000, 1), 256, 0, stream>>>(uefA, Ped, bed,
                                                       (float*)d_out + (size_t)NNODES * 128,
                                                       NEDGES, 64, 256);
}